// Round 11
// baseline (555.416 us; speedup 1.0000x reference)
//
#include <hip/hip_runtime.h>
#include <cfloat>

#define NB   8
#define NC   64
#define NPTS 4096
#define KNN  20
#define CO   64

typedef __attribute__((ext_vector_type(8))) short bf16x8;
typedef __attribute__((ext_vector_type(4))) float f32x4;

#define MFMA(a, b, c) __builtin_amdgcn_mfma_f32_16x16x32_bf16(a, b, c, 0, 0, 0)
#define SB0() __builtin_amdgcn_sched_barrier(0)

// ---------------------------------------------------------------------------
// bf16 helpers (RNE, bit-level; no NaN in this workload)
// ---------------------------------------------------------------------------
__device__ __forceinline__ unsigned short f2bf_rne(float f) {
    unsigned int u = __float_as_uint(f);
    unsigned int r = (u + 0x7FFFu + ((u >> 16) & 1u)) >> 16;
    return (unsigned short)r;
}
__device__ __forceinline__ float bf2f(unsigned short h) {
    return __uint_as_float(((unsigned int)h) << 16);
}
__device__ __forceinline__ unsigned int flip_f(float s) {
    unsigned int b = __float_as_uint(s);
    return (b & 0x80000000u) ? ~b : (b | 0x80000000u);
}
__device__ __forceinline__ float unflip_f(unsigned int u) {
    unsigned int b = (u & 0x80000000u) ? (u ^ 0x80000000u) : ~u;
    return __uint_as_float(b);
}
__device__ __forceinline__ unsigned long long pack_key(float s, int m) {
    return (((unsigned long long)flip_f(s)) << 32) | (unsigned int)m;
}

// ---------------------------------------------------------------------------
// Kernel P1: split x into bf16 triple (h,m,l), INTERLEAVED per point:
// xs[g][0..63]=h, [64..127]=m, [128..191]=l.  x = h+m+l+eps, |eps|<=2^-27|x|.
// ---------------------------------------------------------------------------
__global__ __launch_bounds__(256, 4) void split_kernel(
    const float* __restrict__ x, unsigned short* __restrict__ xs,
    float* __restrict__ xx)
{
    int g = blockIdx.x * 256 + threadIdx.x;
    int b = g >> 12, n = g & 4095;
    const float* xb = x + ((size_t)b << 18) + n;
    float sum = 0.f;
    for (int c8 = 0; c8 < 8; ++c8) {
        bf16x8 hv, mv, lv;
#pragma unroll
        for (int u = 0; u < 8; ++u) {
            float v = xb[(size_t)(c8 * 8 + u) * NPTS];
            sum += v * v;
            unsigned short hb = f2bf_rne(v);
            float r1 = v - bf2f(hb);
            unsigned short mb = f2bf_rne(r1);
            float r2 = r1 - bf2f(mb);
            unsigned short lb = f2bf_rne(r2);
            hv[u] = (short)hb; mv[u] = (short)mb; lv[u] = (short)lb;
        }
        *(bf16x8*)(xs + (size_t)g * 192 + c8 * 8)       = hv;
        *(bf16x8*)(xs + (size_t)g * 192 + 64 + c8 * 8)  = mv;
        *(bf16x8*)(xs + (size_t)g * 192 + 128 + c8 * 8) = lv;
    }
    xx[g] = sum;
}

// ---------------------------------------------------------------------------
// Kernel B: MFMA KNN. Blocks of 2 INDEPENDENT waves (no barriers anywhere;
// LDS partitioned per wave) — packs 2 waves per workgroup slot, since the
// observed residency cap is ~8 workgroups/CU across all 1-wave configs
// (R4/R6/R9/R10 all ~21-23% occupancy regardless of grid). 32 rows/wave.
// Sweep A (approx): h-only, 4-deep reg pipeline, per-lane top-2 per row.
// Cutoff: U20_h + SLACK (|s_exact - s_h| <= 2*sqrt(xx_n*xx_m)*2^-8 < 2.0).
// Sweep B (exact): 6-product f32-exact s, SB0-pinned reg double-buffer,
// ballot-rank appends; EXACT 44-bit-key bisection compaction fallback.
// TRIG=32 >> expected cnt (~26): MAINTAIN rare (R9's TRIG=24 stormed).
// Soundness: post-compact <= 23; entering <= 31; +16 = 47 entries ->
// positions 0..46 <= CAP-1=46; MAINTAIN k0/k1/k2 cover slots 0..46.
// Final: per-row bitonic (15-stage 32-wide fast path when K<=32).
// ---------------------------------------------------------------------------
#define CAP       47
#define TRIG      32
#define SLACK     2.0f

template <int NSP>
__global__ __launch_bounds__(128, 2) void knn_mfma_kernel(
    const unsigned short* __restrict__ xs, const float* __restrict__ xx,
    unsigned long long* __restrict__ ptU)
{
    const int SPLITCOLS = NPTS / NSP;
    const int NT = SPLITCOLS / 16;

    __shared__ unsigned long long bufU[64][CAP];   // 23.5 KB (2 waves x 32 rows)
    __shared__ int cntL[64];

    int tid = threadIdx.x;
    int lane = tid & 63, wid = tid >> 6;           // wid 0..1, independent waves
    int cl = lane & 15, grp = lane >> 4;           // grp 0..3 = k-chunk of 8
    int blk = (int)blockIdx.x;
    int b = blk & 7;                    // batch -> XCD affinity
    int rest = blk >> 3;
    int split = rest >> 6;              // 0..NSP-1
    int rowtile2 = rest & 63;           // 0..63 (64 chunks of 64 rows)
    int n0 = rowtile2 * 64 + wid * 32;  // this wave's 32 rows
    int c_base = split * SPLITCOLS;

    const unsigned short* Xb = xs + ((size_t)b << 12) * 192;
    const float* xxb = xx + ((size_t)b << 12);
    int koff = grp * 8;

    // A fragments: rows n0 + h*16 + cl
    bf16x8 aH[2][2], aM[2][2], aL[2][2];
#pragma unroll
    for (int h = 0; h < 2; ++h) {
        const unsigned short* p = Xb + (size_t)(n0 + h * 16 + cl) * 192 + koff;
        aH[h][0] = *(const bf16x8*)(p);
        aH[h][1] = *(const bf16x8*)(p + 32);
        aM[h][0] = *(const bf16x8*)(p + 64);
        aM[h][1] = *(const bf16x8*)(p + 96);
        aL[h][0] = *(const bf16x8*)(p + 128);
        aL[h][1] = *(const bf16x8*)(p + 160);
    }

    // ---------------- Sweep A: h-only, per-lane top-2 per row ------------
    float m1[8], m2[8];
#pragma unroll
    for (int q = 0; q < 8; ++q) { m1[q] = FLT_MAX; m2[q] = FLT_MAX; }

#define LOADH(HF_, XX_, col) do {                                       \
        const unsigned short* p_ = Xb + (size_t)(col) * 192 + koff;     \
        HF_[0] = *(const bf16x8*)(p_);                                  \
        HF_[1] = *(const bf16x8*)(p_ + 32);                             \
        XX_ = xxb[col];                                                 \
    } while (0)

#define PROCA(HF_, XX_) do {                                            \
    f32x4 a00 = {0.f,0.f,0.f,0.f}, a01 = {0.f,0.f,0.f,0.f};             \
    f32x4 a10 = {0.f,0.f,0.f,0.f}, a11 = {0.f,0.f,0.f,0.f};             \
    a00 = MFMA(aH[0][0], HF_[0], a00);                                  \
    a10 = MFMA(aH[1][0], HF_[0], a10);                                  \
    a01 = MFMA(aH[0][1], HF_[1], a01);                                  \
    a11 = MFMA(aH[1][1], HF_[1], a11);                                  \
    _Pragma("unroll")                                                   \
    for (int j = 0; j < 4; ++j) {                                       \
      float d0 = a00[j] + a01[j], d1 = a10[j] + a11[j];                 \
      float s0 = fmaf(-2.f, d0, XX_);                                   \
      float s1 = fmaf(-2.f, d1, XX_);                                   \
      float t0 = fmaxf(m1[j], s0);                                      \
      m1[j] = fminf(m1[j], s0);                                         \
      m2[j] = fminf(m2[j], t0);                                         \
      float t1 = fmaxf(m1[4 + j], s1);                                  \
      m1[4 + j] = fminf(m1[4 + j], s1);                                 \
      m2[4 + j] = fminf(m2[4 + j], t1);                                 \
    }                                                                   \
} while (0)

    {
        bf16x8 h0[2], h1[2], h2[2], h3[2];
        float xa0, xa1, xa2, xa3;
        LOADH(h0, xa0, c_base + 0 * 16 + cl);
        LOADH(h1, xa1, c_base + 1 * 16 + cl);
        LOADH(h2, xa2, c_base + 2 * 16 + cl);
        for (int t = 0; t < NT; t += 4) {
            LOADH(h3, xa3, c_base + (t + 3) * 16 + cl);
            SB0();
            PROCA(h0, xa0);
            if (t + 4 < NT) LOADH(h0, xa0, c_base + (t + 4) * 16 + cl);
            SB0();
            PROCA(h1, xa1);
            if (t + 5 < NT) LOADH(h1, xa1, c_base + (t + 5) * 16 + cl);
            SB0();
            PROCA(h2, xa2);
            if (t + 6 < NT) LOADH(h2, xa2, c_base + (t + 6) * 16 + cl);
            SB0();
            PROCA(h3, xa3);
        }
    }

    // ------------- cutoff U20_h + SLACK: 16-bit-prefix binary search ----
    float cut[8];
    int   cnt[8];
    {
        unsigned long long gm = 0xFFFFull << (grp << 4);
#pragma unroll
        for (int q = 0; q < 8; ++q) {
            unsigned p1 = flip_f(m1[q]) >> 16;
            unsigned p2 = flip_f(m2[q]) >> 16;
            unsigned lo = 0, hi = 0xFFFFu;
#pragma nounroll
            for (int it = 0; it < 16; ++it) {
                unsigned mid = (lo + hi) >> 1;
                int c2 = (p1 <= mid) + (p2 <= mid);
                unsigned long long bb0 = __ballot((c2 & 1) != 0);
                unsigned long long bb1 = __ballot((c2 & 2) != 0);
                int cc = __popcll(bb0 & gm) + 2 * __popcll(bb1 & gm);
                if (cc >= KNN) hi = mid; else lo = mid + 1;
            }
            cut[q] = (hi == 0xFFFFu) ? FLT_MAX
                                     : unflip_f((hi << 16) | 0xFFFFu) + SLACK;
            cnt[q] = 0;
        }
    }
    bool needm = false;

    bf16x8 B0_[3][2], B1_[3][2];
    float xx0, xx1;

#define LOADB(BF_, XX_, col) do {                                       \
        const unsigned short* p_ = Xb + (size_t)(col) * 192 + koff;     \
        BF_[0][0] = *(const bf16x8*)(p_);                               \
        BF_[0][1] = *(const bf16x8*)(p_ + 32);                          \
        BF_[1][0] = *(const bf16x8*)(p_ + 64);                          \
        BF_[1][1] = *(const bf16x8*)(p_ + 96);                          \
        BF_[2][0] = *(const bf16x8*)(p_ + 128);                         \
        BF_[2][1] = *(const bf16x8*)(p_ + 160);                         \
        XX_ = xxb[col];                                                 \
    } while (0)

#define DOMFMA(B_) \
    f32x4 a00 = {0.f,0.f,0.f,0.f}, a01 = {0.f,0.f,0.f,0.f};             \
    f32x4 a10 = {0.f,0.f,0.f,0.f}, a11 = {0.f,0.f,0.f,0.f};             \
    a00 = MFMA(aH[0][0], B_[0][0], a00);                                \
    a10 = MFMA(aH[1][0], B_[0][0], a10);                                \
    a01 = MFMA(aH[0][1], B_[0][1], a01);                                \
    a11 = MFMA(aH[1][1], B_[0][1], a11);                                \
    a00 = MFMA(aM[0][0], B_[0][0], a00);                                \
    a10 = MFMA(aM[1][0], B_[0][0], a10);                                \
    a01 = MFMA(aM[0][1], B_[0][1], a01);                                \
    a11 = MFMA(aM[1][1], B_[0][1], a11);                                \
    a00 = MFMA(aH[0][0], B_[1][0], a00);                                \
    a10 = MFMA(aH[1][0], B_[1][0], a10);                                \
    a01 = MFMA(aH[0][1], B_[1][1], a01);                                \
    a11 = MFMA(aH[1][1], B_[1][1], a11);                                \
    a00 = MFMA(aM[0][0], B_[1][0], a00);                                \
    a10 = MFMA(aM[1][0], B_[1][0], a10);                                \
    a01 = MFMA(aM[0][1], B_[1][1], a01);                                \
    a11 = MFMA(aM[1][1], B_[1][1], a11);                                \
    a00 = MFMA(aL[0][0], B_[0][0], a00);                                \
    a10 = MFMA(aL[1][0], B_[0][0], a10);                                \
    a01 = MFMA(aL[0][1], B_[0][1], a01);                                \
    a11 = MFMA(aL[1][1], B_[0][1], a11);                                \
    a00 = MFMA(aH[0][0], B_[2][0], a00);                                \
    a10 = MFMA(aH[1][0], B_[2][0], a10);                                \
    a01 = MFMA(aH[0][1], B_[2][1], a01);                                \
    a11 = MFMA(aH[1][1], B_[2][1], a11);

    // ------------- fallback compaction: EXACT 44-bit-key bisection -------
    // key44 = (score32 << 12) | mcol (mcol < 4096 -> unique within a row).
    // Minimal T with count>=20 has count==20; early-break window [20,23].
#define MAINTAIN() do {                                                 \
    _Pragma("unroll")                                                   \
    for (int q = 0; q < 8; ++q) {                                       \
      if (__ballot(cnt[q] >= TRIG)) {                                   \
        bool act = (cnt[q] >= TRIG);                                    \
        int r_ = (wid << 5) + ((q >> 2) << 4) + (grp << 2) + (q & 3);   \
        if (act) {                                                      \
          int K = cnt[q];                                               \
          unsigned long long k0 = bufU[r_][cl];                         \
          unsigned long long k1 = bufU[r_][cl + 16];                    \
          unsigned long long k2 = (cl + 32 < CAP) ? bufU[r_][cl + 32] : ~0ull; \
          unsigned long long v0 = ((k0 >> 32) << 12) | (k0 & 0xFFFull); \
          unsigned long long v1 = ((k1 >> 32) << 12) | (k1 & 0xFFFull); \
          unsigned long long v2 = ((k2 >> 32) << 12) | (k2 & 0xFFFull); \
          const unsigned long long INF44 = (1ull << 44) - 1ull;         \
          if (!(cl      < K)) v0 = INF44;                               \
          if (!(cl + 16 < K)) v1 = INF44;                               \
          if (!(cl + 32 < K)) v2 = INF44;                               \
          unsigned long long gm = 0xFFFFull << (grp << 4);              \
          unsigned long long lo = 0, hi = INF44, T = INF44;             \
          _Pragma("nounroll")                                           \
          for (int it = 0; it < 46 && lo < hi; ++it) {                  \
            unsigned long long mid = lo + ((hi - lo) >> 1);             \
            int c3 = (v0 <= mid) + (v1 <= mid) + (v2 <= mid);           \
            unsigned long long bb0 = __ballot((c3 & 1) != 0);           \
            unsigned long long bb1 = __ballot((c3 & 2) != 0);           \
            int cc = __popcll(bb0 & gm) + 2 * __popcll(bb1 & gm);       \
            if (cc >= KNN && cc <= 23) { T = mid; break; }              \
            if (cc < KNN) lo = mid + 1; else { hi = mid; T = mid; }     \
          }                                                             \
          bool p0 = (v0 <= T);                                          \
          bool p1 = (v1 <= T);                                          \
          bool p2 = (v2 <= T);                                          \
          unsigned long long bq_;                                       \
          bq_ = __ballot(p0); unsigned m0_ = (unsigned)((bq_ >> (grp << 4)) & 0xFFFFull); \
          bq_ = __ballot(p1); unsigned m1_ = (unsigned)((bq_ >> (grp << 4)) & 0xFFFFull); \
          bq_ = __ballot(p2); unsigned m2_ = (unsigned)((bq_ >> (grp << 4)) & 0xFFFFull); \
          int base1 = __popc(m0_), base2 = base1 + __popc(m1_);         \
          int newK = base2 + __popc(m2_);                               \
          unsigned below = (1u << cl) - 1u;                             \
          if (p0) bufU[r_][__popc(m0_ & below)] = k0;                   \
          if (p1) bufU[r_][base1 + __popc(m1_ & below)] = k1;           \
          if (p2) bufU[r_][base2 + __popc(m2_ & below)] = k2;           \
          cnt[q] = newK;                                                \
          cut[q] = unflip_f((unsigned)(T >> 12));                       \
        }                                                               \
      }                                                                 \
    }                                                                   \
} while (0)

    // ---------------- Sweep B: append s <= cut ---------------------------
#define PROCB(B_, XX_, MCOL_) do {                                      \
    DOMFMA(B_)                                                          \
    float s_[8]; bool p_[8];                                            \
    _Pragma("unroll")                                                   \
    for (int j = 0; j < 4; ++j) {                                       \
      float d0 = a00[j] + a01[j], d1 = a10[j] + a11[j];                 \
      s_[j]     = fmaf(-2.f, d0, XX_); p_[j]     = (s_[j]     <= cut[j]);     \
      s_[4 + j] = fmaf(-2.f, d1, XX_); p_[4 + j] = (s_[4 + j] <= cut[4 + j]); \
    }                                                                   \
    bool anyp = p_[0]|p_[1]|p_[2]|p_[3]|p_[4]|p_[5]|p_[6]|p_[7];        \
    if (__ballot(anyp)) {                                               \
      _Pragma("unroll")                                                 \
      for (int q = 0; q < 8; ++q) {                                     \
        unsigned long long bq = __ballot(p_[q]);                        \
        unsigned mq = (unsigned)((bq >> (grp << 4)) & 0xFFFFull);       \
        if (mq) {                                                       \
          int r_ = (wid << 5) + ((q >> 2) << 4) + (grp << 2) + (q & 3); \
          int pos = cnt[q] + __popc(mq & ((1u << cl) - 1u));            \
          if (p_[q]) { if (pos >= CAP) pos = CAP - 1;                   \
                       bufU[r_][pos] = pack_key(s_[q], (MCOL_)); }      \
          cnt[q] += __popc(mq);                                         \
          needm |= (cnt[q] >= TRIG);                                    \
        }                                                               \
      }                                                                 \
      if (__ballot(needm)) { MAINTAIN(); needm = false; }               \
    }                                                                   \
} while (0)

    LOADB(B0_, xx0, c_base + cl);
    for (int t = 0; t < NT; t += 2) {
        LOADB(B1_, xx1, c_base + (t + 1) * 16 + cl);
        SB0();
        PROCB(B0_, xx0, c_base + t * 16 + cl);
        if (t + 2 < NT) LOADB(B0_, xx0, c_base + (t + 2) * 16 + cl);
        SB0();
        PROCB(B1_, xx1, c_base + (t + 1) * 16 + cl);
    }

    // publish per-row counts (intra-wave LDS: DS ops from one wave are
    // processed in order -> no barrier needed; waves are independent)
#pragma unroll
    for (int q = 0; q < 8; ++q)
        if (cl == 0) cntL[(wid << 5) + ((q >> 2) << 4) + (grp << 2) + (q & 3)] = cnt[q];

    // final exact per-row top-20 bitonic; K<=32 fast path (15 vs 21 stages)
#pragma nounroll
    for (int r = 0; r < 32; ++r) {
        int lrow = (wid << 5) + r;
        int K = cntL[lrow];
        if (K > CAP) K = CAP;
        unsigned long long v = (lane < K) ? bufU[lrow][lane] : ~0ull;
        if (K <= 32) {
            // lanes 0..31 hold all candidates; 32-wide bitonic (halves never mix)
#pragma unroll
            for (int k = 2; k <= 32; k <<= 1) {
#pragma unroll
                for (int j = k >> 1; j > 0; j >>= 1) {
                    unsigned long long o = __shfl_xor(v, j);
                    bool takeMin = (((lane & j) == 0) == ((lane & k) == 0));
                    v = ((v <= o) == takeMin) ? v : o;
                }
            }
        } else {
#pragma unroll
            for (int k = 2; k <= 64; k <<= 1) {
#pragma unroll
                for (int j = k >> 1; j > 0; j >>= 1) {
                    unsigned long long o = __shfl_xor(v, j);
                    bool takeMin = (((lane & j) == 0) == ((lane & k) == 0));
                    v = ((v <= o) == takeMin) ? v : o;
                }
            }
        }
        if (lane < KNN)
            ptU[((size_t)split * (NB * NPTS) + ((size_t)b << 12) + (n0 + r)) * KNN + lane] = v;
    }
#undef LOADH
#undef PROCA
#undef LOADB
#undef DOMFMA
#undef MAINTAIN
#undef PROCB
}

// ---------------------------------------------------------------------------
// Kernel M: merge the NSP sorted top-20 lists per row -> final idx.
// ---------------------------------------------------------------------------
template <int NSP>
__global__ void merge_kernel(const unsigned long long* __restrict__ ptU,
                             int* __restrict__ idxout)
{
    int row = blockIdx.x * 256 + threadIdx.x;
    const unsigned long long* L[NSP];
    int p[NSP];
#pragma unroll
    for (int s = 0; s < NSP; ++s) {
        L[s] = ptU + ((size_t)s * (NB * NPTS) + row) * KNN;
        p[s] = 0;
    }
    for (int j = 0; j < KNN; ++j) {
        unsigned long long best = ~0ull; int bs = 0;
#pragma unroll
        for (int s = 0; s < NSP; ++s) {
            unsigned long long k = (p[s] < KNN) ? L[s][p[s]] : ~0ull;
            if (k < best) { best = k; bs = s; }
        }
        ++p[bs];
        idxout[(size_t)row * KNN + j] = (int)(best & 0xffffffffu);
    }
}

// ---------------------------------------------------------------------------
// Kernel A2: per-point y1 = W1*x, y2 = (W2-W1)*x
// ---------------------------------------------------------------------------
__global__ __launch_bounds__(256, 2) void precompute_kernel(
    const float* __restrict__ x, const float* __restrict__ W,
    float* __restrict__ y1, float* __restrict__ y2)
{
    __shared__ float4 wf4[64 * 32];
    int t = threadIdx.x;
    for (int i = 0; i < 8; ++i) {
        int e = t + 256 * i;
        wf4[e] = ((const float4*)W)[e];
    }
    int p = t & 63, og = t >> 6;
    int g = blockIdx.x * 64 + p;
    int b = g >> 12, n = g & 4095;
    const float* xb = x + (size_t)b * NC * NPTS + n;

    float4 xr[16];
#pragma unroll
    for (int c4 = 0; c4 < 16; ++c4) {
        xr[c4].x = xb[(4 * c4 + 0) * NPTS];
        xr[c4].y = xb[(4 * c4 + 1) * NPTS];
        xr[c4].z = xb[(4 * c4 + 2) * NPTS];
        xr[c4].w = xb[(4 * c4 + 3) * NPTS];
    }
    __syncthreads();

    float out1[16], out2[16];
#pragma unroll
    for (int oi = 0; oi < 16; ++oi) {
        int o = og * 16 + oi;
        float a1 = 0.f, a2 = 0.f;
#pragma unroll
        for (int c4 = 0; c4 < 16; ++c4) {
            float4 w1 = wf4[o * 32 + c4];
            float4 w2 = wf4[o * 32 + 16 + c4];
            float4 xv = xr[c4];
            a1 += w1.x * xv.x + w1.y * xv.y + w1.z * xv.z + w1.w * xv.w;
            a2 += w2.x * xv.x + w2.y * xv.y + w2.z * xv.z + w2.w * xv.w;
        }
        out1[oi] = a1;
        out2[oi] = a2 - a1;
    }
    float4* y1p = (float4*)(y1 + (size_t)g * 64 + og * 16);
    float4* y2p = (float4*)(y2 + (size_t)g * 64 + og * 16);
#pragma unroll
    for (int q = 0; q < 4; ++q) {
        y1p[q] = make_float4(out1[4*q], out1[4*q+1], out1[4*q+2], out1[4*q+3]);
        y2p[q] = make_float4(out2[4*q], out2[4*q+1], out2[4*q+2], out2[4*q+3]);
    }
}

// ---------------------------------------------------------------------------
// Kernel C: per-channel sum/sumsq of v = y1[idx]+y2; optionally also emits
// per-(point,o) vmax/vmin planes so the epilogue can stream.
// ---------------------------------------------------------------------------
__global__ __launch_bounds__(256, 4) void stats_kernel(
    const float* __restrict__ y1, const float* __restrict__ y2,
    const int* __restrict__ idx, float* __restrict__ part,
    float* __restrict__ mmax, float* __restrict__ mmin)
{
    int t = threadIdx.x;
    int o = t & 63, p4 = t >> 6;
    int blk = (int)blockIdx.x;
    int g0 = ((blk & 7) * 64 + (blk >> 3)) * 64;
    float s1 = 0.f, s2 = 0.f;
    for (int pi = 0; pi < 16; ++pi) {
        int g = g0 + pi * 4 + p4;
        int b = g >> 12;
        float y2v = y2[(size_t)g * 64 + o];
        const int* ip = idx + (size_t)g * KNN;
        float vmax = -FLT_MAX, vmin = FLT_MAX;
#pragma unroll
        for (int j = 0; j < KNN; ++j) {
            int id = ip[j];
            float v = y1[((size_t)(b << 12) + id) * 64 + o] + y2v;
            s1 += v; s2 += v * v;
            vmax = fmaxf(vmax, v); vmin = fminf(vmin, v);
        }
        if (mmax) {
            mmax[(size_t)g * 64 + o] = vmax;
            mmin[(size_t)g * 64 + o] = vmin;
        }
    }
    __shared__ float red[256];
    red[t] = s1; __syncthreads();
    if (t < 64) part[blockIdx.x * 128 + o] = red[o] + red[64 + o] + red[128 + o] + red[192 + o];
    __syncthreads();
    red[t] = s2; __syncthreads();
    if (t < 64) part[blockIdx.x * 128 + 64 + o] = red[o] + red[64 + o] + red[128 + o] + red[192 + o];
}

__global__ void finalize_stats_kernel(
    const float* __restrict__ part, const float* __restrict__ gamma,
    const float* __restrict__ beta, float* __restrict__ ss)
{
    int t = threadIdx.x;   // 128 threads
    float S = 0.f;
    for (int p = 0; p < 512; ++p) S += part[p * 128 + t];
    __shared__ float sm[128];
    sm[t] = S; __syncthreads();
    if (t < 64) {
        const float inv = 1.f / (float)(NB * NPTS * KNN);
        float mean = sm[t] * inv;
        float var  = sm[64 + t] * inv - mean * mean;
        float scale = gamma[t] * rsqrtf(var + 1e-5f);
        ss[t] = scale;
        ss[64 + t] = beta[t] - mean * scale;
    }
}

// ---------------------------------------------------------------------------
// Kernel E (streaming): affine+relu from minmax planes, transpose, write.
// ---------------------------------------------------------------------------
__global__ __launch_bounds__(256, 4) void epilogue_stream_kernel(
    const float* __restrict__ mmax, const float* __restrict__ mmin,
    const float* __restrict__ ss, float* __restrict__ out)
{
    __shared__ float zT[64][65];
    int t = threadIdx.x;
    int o = t & 63, p4 = t >> 6;
    float sc = ss[o], sh = ss[64 + o];
    int blk = (int)blockIdx.x;
    int g0 = ((blk & 7) * 64 + (blk >> 3)) * 64;
    int b = g0 >> 12, n0 = g0 & 4095;
    for (int pi = 0; pi < 16; ++pi) {
        int pc = pi * 4 + p4;
        int g = g0 + pc;
        float vmax = mmax[(size_t)g * 64 + o];
        float vmin = mmin[(size_t)g * 64 + o];
        float z = (sc >= 0.f) ? sc * vmax + sh : sc * vmin + sh;
        zT[o][pc] = fmaxf(z, 0.f);
    }
    __syncthreads();
    for (int i = 0; i < 16; ++i) {
        int e = t + 256 * i;
        int oo = e >> 6, nn = e & 63;
        out[((size_t)(b * 64 + oo)) * 4096 + n0 + nn] = zT[oo][nn];
    }
}

// Kernel E (gather fallback, small-ws path)
__global__ __launch_bounds__(256, 4) void epilogue_gather_kernel(
    const float* __restrict__ y1, const float* __restrict__ y2,
    const int* __restrict__ idx, const float* __restrict__ ss,
    float* __restrict__ out)
{
    __shared__ float zT[64][65];
    int t = threadIdx.x;
    int o = t & 63, p4 = t >> 6;
    float sc = ss[o], sh = ss[64 + o];
    int blk = (int)blockIdx.x;
    int g0 = ((blk & 7) * 64 + (blk >> 3)) * 64;
    int b = g0 >> 12, n0 = g0 & 4095;
    for (int pi = 0; pi < 16; ++pi) {
        int pc = pi * 4 + p4;
        int g = g0 + pc;
        float y2v = y2[(size_t)g * 64 + o];
        const int* ip = idx + (size_t)g * KNN;
        float vmax = -FLT_MAX, vmin = FLT_MAX;
#pragma unroll
        for (int j = 0; j < KNN; ++j) {
            int id = ip[j];
            float v = y1[((size_t)(b << 12) + id) * 64 + o] + y2v;
            vmax = fmaxf(vmax, v); vmin = fminf(vmin, v);
        }
        float z = (sc >= 0.f) ? sc * vmax + sh : sc * vmin + sh;
        zT[o][pc] = fmaxf(z, 0.f);
    }
    __syncthreads();
    for (int i = 0; i < 16; ++i) {
        int e = t + 256 * i;
        int oo = e >> 6, nn = e & 63;
        out[((size_t)(b * 64 + oo)) * 4096 + n0 + nn] = zT[oo][nn];
    }
}

// ---------------------------------------------------------------------------
extern "C" void kernel_launch(void* const* d_in, const int* in_sizes, int n_in,
                              void* d_out, int out_size, void* d_ws, size_t ws_size,
                              hipStream_t stream)
{
    const float* x     = (const float*)d_in[0];
    const float* W     = (const float*)d_in[1];
    const float* gamma = (const float*)d_in[2];
    const float* beta  = (const float*)d_in[3];
    float* out = (float*)d_out;

    char* ws = (char*)d_ws;
    unsigned short* xs = (unsigned short*)(ws);                     // 12 MB
    unsigned long long* ptU = (unsigned long long*)(ws + 12582912);

    const size_t need4 = 12582912ull + 20971520ull + 2621440ull + 131072ull
                       + 262144ull + 512ull;                        // ~36.6 MB
    const bool big = (ws_size >= need4);
    const size_t ptU_bytes = (big ? 4ull : 2ull) * NB * NPTS * KNN * 8ull;

    char* tail = ws + 12582912 + ptU_bytes;
    int*   idx  = (int*)  (tail);
    float* xx   = (float*)(tail + 2621440);
    float* part = (float*)(tail + 2621440 + 131072);
    float* ss   = (float*)(tail + 2621440 + 131072 + 262144);
    // phase 2 overlays the dead xs+ptU region
    float* y1   = (float*)(ws);                                     // 8 MB
    float* y2   = (float*)(ws + 8388608);                           // 8 MB
    float* mmax = (float*)(ws + 16777216);                          // 8 MB (big only)
    float* mmin = (float*)(ws + 25165824);                          // 8 MB (big only)

    hipLaunchKernelGGL(split_kernel, dim3(128), dim3(256), 0, stream, x, xs, xx);
    if (big) {
        hipLaunchKernelGGL((knn_mfma_kernel<4>), dim3(2048), dim3(128), 0, stream, xs, xx, ptU);
        hipLaunchKernelGGL((merge_kernel<4>),    dim3(128),  dim3(256), 0, stream, ptU, idx);
    } else {
        hipLaunchKernelGGL((knn_mfma_kernel<2>), dim3(1024), dim3(128), 0, stream, xs, xx, ptU);
        hipLaunchKernelGGL((merge_kernel<2>),    dim3(128),  dim3(256), 0, stream, ptU, idx);
    }
    hipLaunchKernelGGL(precompute_kernel, dim3(512), dim3(256), 0, stream, x, W, y1, y2);
    if (big) {
        hipLaunchKernelGGL(stats_kernel,          dim3(512), dim3(256), 0, stream, y1, y2, idx, part, mmax, mmin);
        hipLaunchKernelGGL(finalize_stats_kernel, dim3(1),   dim3(128), 0, stream, part, gamma, beta, ss);
        hipLaunchKernelGGL(epilogue_stream_kernel, dim3(512), dim3(256), 0, stream, mmax, mmin, ss, out);
    } else {
        hipLaunchKernelGGL(stats_kernel,          dim3(512), dim3(256), 0, stream, y1, y2, idx, part, (float*)nullptr, (float*)nullptr);
        hipLaunchKernelGGL(finalize_stats_kernel, dim3(1),   dim3(128), 0, stream, part, gamma, beta, ss);
        hipLaunchKernelGGL(epilogue_gather_kernel, dim3(512), dim3(256), 0, stream, y1, y2, idx, ss, out);
    }
}

// Round 12
// 449.647 us; speedup vs baseline: 1.2352x; 1.2352x over previous
//
#include <hip/hip_runtime.h>
#include <cfloat>

#define NB   8
#define NC   64
#define NPTS 4096
#define KNN  20
#define CO   64

typedef __attribute__((ext_vector_type(8))) short bf16x8;
typedef __attribute__((ext_vector_type(4))) float f32x4;

#define MFMA(a, b, c) __builtin_amdgcn_mfma_f32_16x16x32_bf16(a, b, c, 0, 0, 0)
#define SB0() __builtin_amdgcn_sched_barrier(0)

// ---------------------------------------------------------------------------
// bf16 helpers (RNE, bit-level; no NaN in this workload)
// ---------------------------------------------------------------------------
__device__ __forceinline__ unsigned short f2bf_rne(float f) {
    unsigned int u = __float_as_uint(f);
    unsigned int r = (u + 0x7FFFu + ((u >> 16) & 1u)) >> 16;
    return (unsigned short)r;
}
__device__ __forceinline__ float bf2f(unsigned short h) {
    return __uint_as_float(((unsigned int)h) << 16);
}
__device__ __forceinline__ unsigned int flip_f(float s) {
    unsigned int b = __float_as_uint(s);
    return (b & 0x80000000u) ? ~b : (b | 0x80000000u);
}
__device__ __forceinline__ float unflip_f(unsigned int u) {
    unsigned int b = (u & 0x80000000u) ? (u ^ 0x80000000u) : ~u;
    return __uint_as_float(b);
}
__device__ __forceinline__ unsigned long long pack_key(float s, int m) {
    return (((unsigned long long)flip_f(s)) << 32) | (unsigned int)m;
}

// ---------------------------------------------------------------------------
// BLOCKED xs layout (the R12 change): per batch, 256 tiles of 16 points.
// Tile block = 6144 B: addr(tile, fg, grp, cl) = tile*6144 + fg*1024
//   + grp*256 + cl*16, where fg = f*2 + khalf (f: 0=h,1=m,2=l; khalf: k/32),
//   grp = (k>>3)&3, cl = point within tile. A 64-lane fragment load is then
//   base + lane*16 — one contiguous 1KB burst (8 cache lines), and the 6
//   fragment loads of a tile are immediate offsets 0,1024,...,5120 off one
//   wave-uniform base. The old per-point layout gave every load a 384B
//   inter-lane stride (~16-32 lines per instruction) which saturated the
//   vector-memory request pipe (R6->R10: more waves didn't help; VALU-busy
//   TIME constant across configs -> shared-resource bound).
// x = h+m+l+eps, |eps|<=2^-27|x|.
// ---------------------------------------------------------------------------
__global__ __launch_bounds__(256, 4) void split_kernel(
    const float* __restrict__ x, unsigned short* __restrict__ xs,
    float* __restrict__ xx)
{
    int g = blockIdx.x * 256 + threadIdx.x;
    int b = g >> 12, n = g & 4095;
    const float* xb = x + ((size_t)b << 18) + n;
    char* xsb = (char*)xs;
    size_t base0 = (size_t)b * 1572864 + (size_t)(n >> 4) * 6144 + (size_t)(n & 15) * 16;
    float sum = 0.f;
    for (int c8 = 0; c8 < 8; ++c8) {        // k-chunk: khalf=c8>>2, grp=c8&3
        bf16x8 hv, mv, lv;
#pragma unroll
        for (int u = 0; u < 8; ++u) {
            float v = xb[(size_t)(c8 * 8 + u) * NPTS];
            sum += v * v;
            unsigned short hb = f2bf_rne(v);
            float r1 = v - bf2f(hb);
            unsigned short mb = f2bf_rne(r1);
            float r2 = r1 - bf2f(mb);
            unsigned short lb = f2bf_rne(r2);
            hv[u] = (short)hb; mv[u] = (short)mb; lv[u] = (short)lb;
        }
        int half = c8 >> 2, grp = c8 & 3;
        size_t off = base0 + (size_t)grp * 256;
        *(bf16x8*)(xsb + off + (size_t)(0 * 2 + half) * 1024) = hv;
        *(bf16x8*)(xsb + off + (size_t)(1 * 2 + half) * 1024) = mv;
        *(bf16x8*)(xsb + off + (size_t)(2 * 2 + half) * 1024) = lv;
    }
    xx[g] = sum;
}

// ---------------------------------------------------------------------------
// Kernel B: MFMA KNN. 1-wave blocks (R10 config — best so far at 438 µs),
// 32 rows/wave, NSP column splits. Sweep A (approx): h-only, 4-deep reg
// pipeline, per-lane top-2 per row. Cutoff: U20_h + SLACK (error bound
// 2*sqrt(xx_n*xx_m)*2^-8 < 2.0). Sweep B (exact): 6-product f32-exact s,
// SB0-pinned reg double-buffer, ballot-rank appends; EXACT 44-bit-key
// bisection compaction fallback (TRIG=32 >> expected cnt ~26: rare).
// Soundness: post-compact <= 23; entering <= 31; +16 = 47 < CAP=48.
// All loads coalesced via the blocked layout. Final: per-row bitonic
// (15-stage 32-wide fast path when K<=32).
// ---------------------------------------------------------------------------
#define CAP       48
#define TRIG      32
#define SLACK     2.0f

template <int NSP>
__global__ __launch_bounds__(64, 2) void knn_mfma_kernel(
    const unsigned short* __restrict__ xs, const float* __restrict__ xx,
    unsigned long long* __restrict__ ptU)
{
    const int SPLITCOLS = NPTS / NSP;
    const int NT = SPLITCOLS / 16;

    __shared__ unsigned long long bufU[32][CAP];   // 12.3 KB
    __shared__ int cntL[32];

    int lane = threadIdx.x;
    int cl = lane & 15, grp = lane >> 4;           // grp 0..3 = k-chunk of 8
    int blk = (int)blockIdx.x;
    int b = blk & 7;                    // batch -> XCD affinity
    int rt = blk >> 3;
    int n0 = (rt & 127) * 32;           // row tile within batch
    int split = rt >> 7;                // 0..NSP-1
    int c_base = split * SPLITCOLS;
    const int tbase = split * (SPLITCOLS >> 4);

    const char* XbB = (const char*)xs + (size_t)b * 1572864;
    const float* xxb = xx + ((size_t)b << 12);

    // A fragments: rows n0 + h*16 + cl (row tile (n0>>4)+h, lane*16 in-block)
    bf16x8 aH[2][2], aM[2][2], aL[2][2];
#pragma unroll
    for (int h = 0; h < 2; ++h) {
        const char* pa = XbB + (size_t)((n0 >> 4) + h) * 6144 + lane * 16;
        aH[h][0] = *(const bf16x8*)(pa);
        aH[h][1] = *(const bf16x8*)(pa + 1024);
        aM[h][0] = *(const bf16x8*)(pa + 2048);
        aM[h][1] = *(const bf16x8*)(pa + 3072);
        aL[h][0] = *(const bf16x8*)(pa + 4096);
        aL[h][1] = *(const bf16x8*)(pa + 5120);
    }

    // ---------------- Sweep A: h-only, per-lane top-2 per row ------------
    float m1[8], m2[8];
#pragma unroll
    for (int q = 0; q < 8; ++q) { m1[q] = FLT_MAX; m2[q] = FLT_MAX; }

#define LOADH(HF_, XX_, tt) do {                                        \
        const char* p_ = XbB + (size_t)(tbase + (tt)) * 6144 + lane * 16; \
        HF_[0] = *(const bf16x8*)(p_);                                  \
        HF_[1] = *(const bf16x8*)(p_ + 1024);                           \
        XX_ = xxb[((tbase + (tt)) << 4) + cl];                          \
    } while (0)

#define PROCA(HF_, XX_) do {                                            \
    f32x4 a00 = {0.f,0.f,0.f,0.f}, a01 = {0.f,0.f,0.f,0.f};             \
    f32x4 a10 = {0.f,0.f,0.f,0.f}, a11 = {0.f,0.f,0.f,0.f};             \
    a00 = MFMA(aH[0][0], HF_[0], a00);                                  \
    a10 = MFMA(aH[1][0], HF_[0], a10);                                  \
    a01 = MFMA(aH[0][1], HF_[1], a01);                                  \
    a11 = MFMA(aH[1][1], HF_[1], a11);                                  \
    _Pragma("unroll")                                                   \
    for (int j = 0; j < 4; ++j) {                                       \
      float d0 = a00[j] + a01[j], d1 = a10[j] + a11[j];                 \
      float s0 = fmaf(-2.f, d0, XX_);                                   \
      float s1 = fmaf(-2.f, d1, XX_);                                   \
      float t0 = fmaxf(m1[j], s0);                                      \
      m1[j] = fminf(m1[j], s0);                                         \
      m2[j] = fminf(m2[j], t0);                                         \
      float t1 = fmaxf(m1[4 + j], s1);                                  \
      m1[4 + j] = fminf(m1[4 + j], s1);                                 \
      m2[4 + j] = fminf(m2[4 + j], t1);                                 \
    }                                                                   \
} while (0)

    {
        bf16x8 h0[2], h1[2], h2[2], h3[2];
        float xa0, xa1, xa2, xa3;
        LOADH(h0, xa0, 0);
        LOADH(h1, xa1, 1);
        LOADH(h2, xa2, 2);
        for (int t = 0; t < NT; t += 4) {
            LOADH(h3, xa3, t + 3);
            SB0();
            PROCA(h0, xa0);
            if (t + 4 < NT) LOADH(h0, xa0, t + 4);
            SB0();
            PROCA(h1, xa1);
            if (t + 5 < NT) LOADH(h1, xa1, t + 5);
            SB0();
            PROCA(h2, xa2);
            if (t + 6 < NT) LOADH(h2, xa2, t + 6);
            SB0();
            PROCA(h3, xa3);
        }
    }

    // ------------- cutoff U20_h + SLACK: 16-bit-prefix binary search ----
    float cut[8];
    int   cnt[8];
    {
        unsigned long long gm = 0xFFFFull << (grp << 4);
#pragma unroll
        for (int q = 0; q < 8; ++q) {
            unsigned p1 = flip_f(m1[q]) >> 16;
            unsigned p2 = flip_f(m2[q]) >> 16;
            unsigned lo = 0, hi = 0xFFFFu;
#pragma nounroll
            for (int it = 0; it < 16; ++it) {
                unsigned mid = (lo + hi) >> 1;
                int c2 = (p1 <= mid) + (p2 <= mid);
                unsigned long long bb0 = __ballot((c2 & 1) != 0);
                unsigned long long bb1 = __ballot((c2 & 2) != 0);
                int cc = __popcll(bb0 & gm) + 2 * __popcll(bb1 & gm);
                if (cc >= KNN) hi = mid; else lo = mid + 1;
            }
            cut[q] = (hi == 0xFFFFu) ? FLT_MAX
                                     : unflip_f((hi << 16) | 0xFFFFu) + SLACK;
            cnt[q] = 0;
        }
    }
    bool needm = false;

    bf16x8 B0_[3][2], B1_[3][2];
    float xx0, xx1;

#define LOADB(BF_, XX_, tt) do {                                        \
        const char* p_ = XbB + (size_t)(tbase + (tt)) * 6144 + lane * 16; \
        BF_[0][0] = *(const bf16x8*)(p_);                               \
        BF_[0][1] = *(const bf16x8*)(p_ + 1024);                        \
        BF_[1][0] = *(const bf16x8*)(p_ + 2048);                        \
        BF_[1][1] = *(const bf16x8*)(p_ + 3072);                        \
        BF_[2][0] = *(const bf16x8*)(p_ + 4096);                        \
        BF_[2][1] = *(const bf16x8*)(p_ + 5120);                        \
        XX_ = xxb[((tbase + (tt)) << 4) + cl];                          \
    } while (0)

#define DOMFMA(B_) \
    f32x4 a00 = {0.f,0.f,0.f,0.f}, a01 = {0.f,0.f,0.f,0.f};             \
    f32x4 a10 = {0.f,0.f,0.f,0.f}, a11 = {0.f,0.f,0.f,0.f};             \
    a00 = MFMA(aH[0][0], B_[0][0], a00);                                \
    a10 = MFMA(aH[1][0], B_[0][0], a10);                                \
    a01 = MFMA(aH[0][1], B_[0][1], a01);                                \
    a11 = MFMA(aH[1][1], B_[0][1], a11);                                \
    a00 = MFMA(aM[0][0], B_[0][0], a00);                                \
    a10 = MFMA(aM[1][0], B_[0][0], a10);                                \
    a01 = MFMA(aM[0][1], B_[0][1], a01);                                \
    a11 = MFMA(aM[1][1], B_[0][1], a11);                                \
    a00 = MFMA(aH[0][0], B_[1][0], a00);                                \
    a10 = MFMA(aH[1][0], B_[1][0], a10);                                \
    a01 = MFMA(aH[0][1], B_[1][1], a01);                                \
    a11 = MFMA(aH[1][1], B_[1][1], a11);                                \
    a00 = MFMA(aM[0][0], B_[1][0], a00);                                \
    a10 = MFMA(aM[1][0], B_[1][0], a10);                                \
    a01 = MFMA(aM[0][1], B_[1][1], a01);                                \
    a11 = MFMA(aM[1][1], B_[1][1], a11);                                \
    a00 = MFMA(aL[0][0], B_[0][0], a00);                                \
    a10 = MFMA(aL[1][0], B_[0][0], a10);                                \
    a01 = MFMA(aL[0][1], B_[0][1], a01);                                \
    a11 = MFMA(aL[1][1], B_[0][1], a11);                                \
    a00 = MFMA(aH[0][0], B_[2][0], a00);                                \
    a10 = MFMA(aH[1][0], B_[2][0], a10);                                \
    a01 = MFMA(aH[0][1], B_[2][1], a01);                                \
    a11 = MFMA(aH[1][1], B_[2][1], a11);

    // ------------- fallback compaction: EXACT 44-bit-key bisection -------
    // key44 = (score32 << 12) | mcol (mcol < 4096 -> unique within a row).
    // Minimal T with count>=20 has count==20; early-break window [20,23].
#define MAINTAIN() do {                                                 \
    _Pragma("unroll")                                                   \
    for (int q = 0; q < 8; ++q) {                                       \
      if (__ballot(cnt[q] >= TRIG)) {                                   \
        bool act = (cnt[q] >= TRIG);                                    \
        int r_ = ((q >> 2) << 4) + (grp << 2) + (q & 3);                \
        if (act) {                                                      \
          int K = cnt[q];                                               \
          unsigned long long k0 = bufU[r_][cl];                         \
          unsigned long long k1 = bufU[r_][cl + 16];                    \
          unsigned long long k2 = (cl + 32 < CAP) ? bufU[r_][cl + 32] : ~0ull; \
          unsigned long long v0 = ((k0 >> 32) << 12) | (k0 & 0xFFFull); \
          unsigned long long v1 = ((k1 >> 32) << 12) | (k1 & 0xFFFull); \
          unsigned long long v2 = ((k2 >> 32) << 12) | (k2 & 0xFFFull); \
          const unsigned long long INF44 = (1ull << 44) - 1ull;         \
          if (!(cl      < K)) v0 = INF44;                               \
          if (!(cl + 16 < K)) v1 = INF44;                               \
          if (!(cl + 32 < K)) v2 = INF44;                               \
          unsigned long long gm = 0xFFFFull << (grp << 4);              \
          unsigned long long lo = 0, hi = INF44, T = INF44;             \
          _Pragma("nounroll")                                           \
          for (int it = 0; it < 46 && lo < hi; ++it) {                  \
            unsigned long long mid = lo + ((hi - lo) >> 1);             \
            int c3 = (v0 <= mid) + (v1 <= mid) + (v2 <= mid);           \
            unsigned long long bb0 = __ballot((c3 & 1) != 0);           \
            unsigned long long bb1 = __ballot((c3 & 2) != 0);           \
            int cc = __popcll(bb0 & gm) + 2 * __popcll(bb1 & gm);       \
            if (cc >= KNN && cc <= 23) { T = mid; break; }              \
            if (cc < KNN) lo = mid + 1; else { hi = mid; T = mid; }     \
          }                                                             \
          bool p0 = (v0 <= T);                                          \
          bool p1 = (v1 <= T);                                          \
          bool p2 = (v2 <= T);                                          \
          unsigned long long bq_;                                       \
          bq_ = __ballot(p0); unsigned m0_ = (unsigned)((bq_ >> (grp << 4)) & 0xFFFFull); \
          bq_ = __ballot(p1); unsigned m1_ = (unsigned)((bq_ >> (grp << 4)) & 0xFFFFull); \
          bq_ = __ballot(p2); unsigned m2_ = (unsigned)((bq_ >> (grp << 4)) & 0xFFFFull); \
          int base1 = __popc(m0_), base2 = base1 + __popc(m1_);         \
          int newK = base2 + __popc(m2_);                               \
          unsigned below = (1u << cl) - 1u;                             \
          if (p0) bufU[r_][__popc(m0_ & below)] = k0;                   \
          if (p1) bufU[r_][base1 + __popc(m1_ & below)] = k1;           \
          if (p2) bufU[r_][base2 + __popc(m2_ & below)] = k2;           \
          cnt[q] = newK;                                                \
          cut[q] = unflip_f((unsigned)(T >> 12));                       \
        }                                                               \
      }                                                                 \
    }                                                                   \
} while (0)

    // ---------------- Sweep B: append s <= cut ---------------------------
#define PROCB(B_, XX_, MCOL_) do {                                      \
    DOMFMA(B_)                                                          \
    float s_[8]; bool p_[8];                                            \
    _Pragma("unroll")                                                   \
    for (int j = 0; j < 4; ++j) {                                       \
      float d0 = a00[j] + a01[j], d1 = a10[j] + a11[j];                 \
      s_[j]     = fmaf(-2.f, d0, XX_); p_[j]     = (s_[j]     <= cut[j]);     \
      s_[4 + j] = fmaf(-2.f, d1, XX_); p_[4 + j] = (s_[4 + j] <= cut[4 + j]); \
    }                                                                   \
    bool anyp = p_[0]|p_[1]|p_[2]|p_[3]|p_[4]|p_[5]|p_[6]|p_[7];        \
    if (__ballot(anyp)) {                                               \
      _Pragma("unroll")                                                 \
      for (int q = 0; q < 8; ++q) {                                     \
        unsigned long long bq = __ballot(p_[q]);                        \
        unsigned mq = (unsigned)((bq >> (grp << 4)) & 0xFFFFull);       \
        if (mq) {                                                       \
          int r_ = ((q >> 2) << 4) + (grp << 2) + (q & 3);              \
          int pos = cnt[q] + __popc(mq & ((1u << cl) - 1u));            \
          if (p_[q]) { if (pos >= CAP) pos = CAP - 1;                   \
                       bufU[r_][pos] = pack_key(s_[q], (MCOL_)); }      \
          cnt[q] += __popc(mq);                                         \
          needm |= (cnt[q] >= TRIG);                                    \
        }                                                               \
      }                                                                 \
      if (__ballot(needm)) { MAINTAIN(); needm = false; }               \
    }                                                                   \
} while (0)

    LOADB(B0_, xx0, 0);
    for (int t = 0; t < NT; t += 2) {
        LOADB(B1_, xx1, t + 1);
        SB0();
        PROCB(B0_, xx0, c_base + t * 16 + cl);
        if (t + 2 < NT) LOADB(B0_, xx0, t + 2);
        SB0();
        PROCB(B1_, xx1, c_base + (t + 1) * 16 + cl);
    }

    // publish per-row counts
#pragma unroll
    for (int q = 0; q < 8; ++q)
        if (cl == 0) cntL[((q >> 2) << 4) + (grp << 2) + (q & 3)] = cnt[q];
    __syncthreads();

    // final exact per-row top-20 bitonic; K<=32 fast path (15 vs 21 stages)
#pragma nounroll
    for (int r = 0; r < 32; ++r) {
        int K = cntL[r];
        if (K > CAP) K = CAP;
        unsigned long long v = (lane < K) ? bufU[r][lane] : ~0ull;
        if (K <= 32) {
#pragma unroll
            for (int k = 2; k <= 32; k <<= 1) {
#pragma unroll
                for (int j = k >> 1; j > 0; j >>= 1) {
                    unsigned long long o = __shfl_xor(v, j);
                    bool takeMin = (((lane & j) == 0) == ((lane & k) == 0));
                    v = ((v <= o) == takeMin) ? v : o;
                }
            }
        } else {
#pragma unroll
            for (int k = 2; k <= 64; k <<= 1) {
#pragma unroll
                for (int j = k >> 1; j > 0; j >>= 1) {
                    unsigned long long o = __shfl_xor(v, j);
                    bool takeMin = (((lane & j) == 0) == ((lane & k) == 0));
                    v = ((v <= o) == takeMin) ? v : o;
                }
            }
        }
        if (lane < KNN)
            ptU[((size_t)split * (NB * NPTS) + ((size_t)b << 12) + (n0 + r)) * KNN + lane] = v;
    }
#undef LOADH
#undef PROCA
#undef LOADB
#undef DOMFMA
#undef MAINTAIN
#undef PROCB
}

// ---------------------------------------------------------------------------
// Kernel M: merge the NSP sorted top-20 lists per row -> final idx.
// ---------------------------------------------------------------------------
template <int NSP>
__global__ void merge_kernel(const unsigned long long* __restrict__ ptU,
                             int* __restrict__ idxout)
{
    int row = blockIdx.x * 256 + threadIdx.x;
    const unsigned long long* L[NSP];
    int p[NSP];
#pragma unroll
    for (int s = 0; s < NSP; ++s) {
        L[s] = ptU + ((size_t)s * (NB * NPTS) + row) * KNN;
        p[s] = 0;
    }
    for (int j = 0; j < KNN; ++j) {
        unsigned long long best = ~0ull; int bs = 0;
#pragma unroll
        for (int s = 0; s < NSP; ++s) {
            unsigned long long k = (p[s] < KNN) ? L[s][p[s]] : ~0ull;
            if (k < best) { best = k; bs = s; }
        }
        ++p[bs];
        idxout[(size_t)row * KNN + j] = (int)(best & 0xffffffffu);
    }
}

// ---------------------------------------------------------------------------
// Kernel A2: per-point y1 = W1*x, y2 = (W2-W1)*x
// ---------------------------------------------------------------------------
__global__ __launch_bounds__(256, 2) void precompute_kernel(
    const float* __restrict__ x, const float* __restrict__ W,
    float* __restrict__ y1, float* __restrict__ y2)
{
    __shared__ float4 wf4[64 * 32];
    int t = threadIdx.x;
    for (int i = 0; i < 8; ++i) {
        int e = t + 256 * i;
        wf4[e] = ((const float4*)W)[e];
    }
    int p = t & 63, og = t >> 6;
    int g = blockIdx.x * 64 + p;
    int b = g >> 12, n = g & 4095;
    const float* xb = x + (size_t)b * NC * NPTS + n;

    float4 xr[16];
#pragma unroll
    for (int c4 = 0; c4 < 16; ++c4) {
        xr[c4].x = xb[(4 * c4 + 0) * NPTS];
        xr[c4].y = xb[(4 * c4 + 1) * NPTS];
        xr[c4].z = xb[(4 * c4 + 2) * NPTS];
        xr[c4].w = xb[(4 * c4 + 3) * NPTS];
    }
    __syncthreads();

    float out1[16], out2[16];
#pragma unroll
    for (int oi = 0; oi < 16; ++oi) {
        int o = og * 16 + oi;
        float a1 = 0.f, a2 = 0.f;
#pragma unroll
        for (int c4 = 0; c4 < 16; ++c4) {
            float4 w1 = wf4[o * 32 + c4];
            float4 w2 = wf4[o * 32 + 16 + c4];
            float4 xv = xr[c4];
            a1 += w1.x * xv.x + w1.y * xv.y + w1.z * xv.z + w1.w * xv.w;
            a2 += w2.x * xv.x + w2.y * xv.y + w2.z * xv.z + w2.w * xv.w;
        }
        out1[oi] = a1;
        out2[oi] = a2 - a1;
    }
    float4* y1p = (float4*)(y1 + (size_t)g * 64 + og * 16);
    float4* y2p = (float4*)(y2 + (size_t)g * 64 + og * 16);
#pragma unroll
    for (int q = 0; q < 4; ++q) {
        y1p[q] = make_float4(out1[4*q], out1[4*q+1], out1[4*q+2], out1[4*q+3]);
        y2p[q] = make_float4(out2[4*q], out2[4*q+1], out2[4*q+2], out2[4*q+3]);
    }
}

// ---------------------------------------------------------------------------
// Kernel C: per-channel sum/sumsq of v = y1[idx]+y2; optionally also emits
// per-(point,o) vmax/vmin planes so the epilogue can stream.
// ---------------------------------------------------------------------------
__global__ __launch_bounds__(256, 4) void stats_kernel(
    const float* __restrict__ y1, const float* __restrict__ y2,
    const int* __restrict__ idx, float* __restrict__ part,
    float* __restrict__ mmax, float* __restrict__ mmin)
{
    int t = threadIdx.x;
    int o = t & 63, p4 = t >> 6;
    int blk = (int)blockIdx.x;
    int g0 = ((blk & 7) * 64 + (blk >> 3)) * 64;
    float s1 = 0.f, s2 = 0.f;
    for (int pi = 0; pi < 16; ++pi) {
        int g = g0 + pi * 4 + p4;
        int b = g >> 12;
        float y2v = y2[(size_t)g * 64 + o];
        const int* ip = idx + (size_t)g * KNN;
        float vmax = -FLT_MAX, vmin = FLT_MAX;
#pragma unroll
        for (int j = 0; j < KNN; ++j) {
            int id = ip[j];
            float v = y1[((size_t)(b << 12) + id) * 64 + o] + y2v;
            s1 += v; s2 += v * v;
            vmax = fmaxf(vmax, v); vmin = fminf(vmin, v);
        }
        if (mmax) {
            mmax[(size_t)g * 64 + o] = vmax;
            mmin[(size_t)g * 64 + o] = vmin;
        }
    }
    __shared__ float red[256];
    red[t] = s1; __syncthreads();
    if (t < 64) part[blockIdx.x * 128 + o] = red[o] + red[64 + o] + red[128 + o] + red[192 + o];
    __syncthreads();
    red[t] = s2; __syncthreads();
    if (t < 64) part[blockIdx.x * 128 + 64 + o] = red[o] + red[64 + o] + red[128 + o] + red[192 + o];
}

__global__ void finalize_stats_kernel(
    const float* __restrict__ part, const float* __restrict__ gamma,
    const float* __restrict__ beta, float* __restrict__ ss)
{
    int t = threadIdx.x;   // 128 threads
    float S = 0.f;
    for (int p = 0; p < 512; ++p) S += part[p * 128 + t];
    __shared__ float sm[128];
    sm[t] = S; __syncthreads();
    if (t < 64) {
        const float inv = 1.f / (float)(NB * NPTS * KNN);
        float mean = sm[t] * inv;
        float var  = sm[64 + t] * inv - mean * mean;
        float scale = gamma[t] * rsqrtf(var + 1e-5f);
        ss[t] = scale;
        ss[64 + t] = beta[t] - mean * scale;
    }
}

// ---------------------------------------------------------------------------
// Kernel E (streaming): affine+relu from minmax planes, transpose, write.
// ---------------------------------------------------------------------------
__global__ __launch_bounds__(256, 4) void epilogue_stream_kernel(
    const float* __restrict__ mmax, const float* __restrict__ mmin,
    const float* __restrict__ ss, float* __restrict__ out)
{
    __shared__ float zT[64][65];
    int t = threadIdx.x;
    int o = t & 63, p4 = t >> 6;
    float sc = ss[o], sh = ss[64 + o];
    int blk = (int)blockIdx.x;
    int g0 = ((blk & 7) * 64 + (blk >> 3)) * 64;
    int b = g0 >> 12, n0 = g0 & 4095;
    for (int pi = 0; pi < 16; ++pi) {
        int pc = pi * 4 + p4;
        int g = g0 + pc;
        float vmax = mmax[(size_t)g * 64 + o];
        float vmin = mmin[(size_t)g * 64 + o];
        float z = (sc >= 0.f) ? sc * vmax + sh : sc * vmin + sh;
        zT[o][pc] = fmaxf(z, 0.f);
    }
    __syncthreads();
    for (int i = 0; i < 16; ++i) {
        int e = t + 256 * i;
        int oo = e >> 6, nn = e & 63;
        out[((size_t)(b * 64 + oo)) * 4096 + n0 + nn] = zT[oo][nn];
    }
}

// Kernel E (gather fallback, small-ws path)
__global__ __launch_bounds__(256, 4) void epilogue_gather_kernel(
    const float* __restrict__ y1, const float* __restrict__ y2,
    const int* __restrict__ idx, const float* __restrict__ ss,
    float* __restrict__ out)
{
    __shared__ float zT[64][65];
    int t = threadIdx.x;
    int o = t & 63, p4 = t >> 6;
    float sc = ss[o], sh = ss[64 + o];
    int blk = (int)blockIdx.x;
    int g0 = ((blk & 7) * 64 + (blk >> 3)) * 64;
    int b = g0 >> 12, n0 = g0 & 4095;
    for (int pi = 0; pi < 16; ++pi) {
        int pc = pi * 4 + p4;
        int g = g0 + pc;
        float y2v = y2[(size_t)g * 64 + o];
        const int* ip = idx + (size_t)g * KNN;
        float vmax = -FLT_MAX, vmin = FLT_MAX;
#pragma unroll
        for (int j = 0; j < KNN; ++j) {
            int id = ip[j];
            float v = y1[((size_t)(b << 12) + id) * 64 + o] + y2v;
            vmax = fmaxf(vmax, v); vmin = fminf(vmin, v);
        }
        float z = (sc >= 0.f) ? sc * vmax + sh : sc * vmin + sh;
        zT[o][pc] = fmaxf(z, 0.f);
    }
    __syncthreads();
    for (int i = 0; i < 16; ++i) {
        int e = t + 256 * i;
        int oo = e >> 6, nn = e & 63;
        out[((size_t)(b * 64 + oo)) * 4096 + n0 + nn] = zT[oo][nn];
    }
}

// ---------------------------------------------------------------------------
extern "C" void kernel_launch(void* const* d_in, const int* in_sizes, int n_in,
                              void* d_out, int out_size, void* d_ws, size_t ws_size,
                              hipStream_t stream)
{
    const float* x     = (const float*)d_in[0];
    const float* W     = (const float*)d_in[1];
    const float* gamma = (const float*)d_in[2];
    const float* beta  = (const float*)d_in[3];
    float* out = (float*)d_out;

    char* ws = (char*)d_ws;
    unsigned short* xs = (unsigned short*)(ws);                     // 12 MB
    unsigned long long* ptU = (unsigned long long*)(ws + 12582912);

    const size_t need4 = 12582912ull + 20971520ull + 2621440ull + 131072ull
                       + 262144ull + 512ull;                        // ~36.6 MB
    const bool big = (ws_size >= need4);
    const size_t ptU_bytes = (big ? 4ull : 2ull) * NB * NPTS * KNN * 8ull;

    char* tail = ws + 12582912 + ptU_bytes;
    int*   idx  = (int*)  (tail);
    float* xx   = (float*)(tail + 2621440);
    float* part = (float*)(tail + 2621440 + 131072);
    float* ss   = (float*)(tail + 2621440 + 131072 + 262144);
    // phase 2 overlays the dead xs+ptU region
    float* y1   = (float*)(ws);                                     // 8 MB
    float* y2   = (float*)(ws + 8388608);                           // 8 MB
    float* mmax = (float*)(ws + 16777216);                          // 8 MB (big only)
    float* mmin = (float*)(ws + 25165824);                          // 8 MB (big only)

    hipLaunchKernelGGL(split_kernel, dim3(128), dim3(256), 0, stream, x, xs, xx);
    if (big) {
        hipLaunchKernelGGL((knn_mfma_kernel<4>), dim3(4096), dim3(64), 0, stream, xs, xx, ptU);
        hipLaunchKernelGGL((merge_kernel<4>),    dim3(128),  dim3(256), 0, stream, ptU, idx);
    } else {
        hipLaunchKernelGGL((knn_mfma_kernel<2>), dim3(2048), dim3(64), 0, stream, xs, xx, ptU);
        hipLaunchKernelGGL((merge_kernel<2>),    dim3(128),  dim3(256), 0, stream, ptU, idx);
    }
    hipLaunchKernelGGL(precompute_kernel, dim3(512), dim3(256), 0, stream, x, W, y1, y2);
    if (big) {
        hipLaunchKernelGGL(stats_kernel,          dim3(512), dim3(256), 0, stream, y1, y2, idx, part, mmax, mmin);
        hipLaunchKernelGGL(finalize_stats_kernel, dim3(1),   dim3(128), 0, stream, part, gamma, beta, ss);
        hipLaunchKernelGGL(epilogue_stream_kernel, dim3(512), dim3(256), 0, stream, mmax, mmin, ss, out);
    } else {
        hipLaunchKernelGGL(stats_kernel,          dim3(512), dim3(256), 0, stream, y1, y2, idx, part, (float*)nullptr, (float*)nullptr);
        hipLaunchKernelGGL(finalize_stats_kernel, dim3(1),   dim3(128), 0, stream, part, gamma, beta, ss);
        hipLaunchKernelGGL(epilogue_gather_kernel, dim3(512), dim3(256), 0, stream, y1, y2, idx, ss, out);
    }
}

// Round 13
// 351.220 us; speedup vs baseline: 1.5814x; 1.2802x over previous
//
#include <hip/hip_runtime.h>
#include <cfloat>

#define NB   8
#define NC   64
#define NPTS 4096
#define KNN  20
#define CO   64

typedef __attribute__((ext_vector_type(8))) short bf16x8;
typedef __attribute__((ext_vector_type(4))) float f32x4;

#define MFMA(a, b, c) __builtin_amdgcn_mfma_f32_16x16x32_bf16(a, b, c, 0, 0, 0)
#define SB0() __builtin_amdgcn_sched_barrier(0)

// ---------------------------------------------------------------------------
// bf16 helpers (RNE, bit-level; no NaN in this workload)
// ---------------------------------------------------------------------------
__device__ __forceinline__ unsigned short f2bf_rne(float f) {
    unsigned int u = __float_as_uint(f);
    unsigned int r = (u + 0x7FFFu + ((u >> 16) & 1u)) >> 16;
    return (unsigned short)r;
}
__device__ __forceinline__ float bf2f(unsigned short h) {
    return __uint_as_float(((unsigned int)h) << 16);
}
__device__ __forceinline__ unsigned int flip_f(float s) {
    unsigned int b = __float_as_uint(s);
    return (b & 0x80000000u) ? ~b : (b | 0x80000000u);
}
__device__ __forceinline__ float unflip_f(unsigned int u) {
    unsigned int b = (u & 0x80000000u) ? (u ^ 0x80000000u) : ~u;
    return __uint_as_float(b);
}
__device__ __forceinline__ unsigned long long pack_key(float s, int m) {
    return (((unsigned long long)flip_f(s)) << 32) | (unsigned int)m;
}

// ---------------------------------------------------------------------------
// BLOCKED xs layout (R12, kept): per batch, 256 tiles of 16 points.
// addr(tile, fg, grp, cl) = tile*6144 + fg*1024 + grp*256 + cl*16,
// fg = f*2 + khalf (f: 0=h,1=m,2=l). A 64-lane fragment load = base+lane*16:
// one contiguous 1KB burst; 6 fragment loads = imm offsets 0..5120.
// x = h+m+l+eps, |eps|<=2^-27|x|.
// ---------------------------------------------------------------------------
__global__ __launch_bounds__(256, 4) void split_kernel(
    const float* __restrict__ x, unsigned short* __restrict__ xs,
    float* __restrict__ xx)
{
    int g = blockIdx.x * 256 + threadIdx.x;
    int b = g >> 12, n = g & 4095;
    const float* xb = x + ((size_t)b << 18) + n;
    char* xsb = (char*)xs;
    size_t base0 = (size_t)b * 1572864 + (size_t)(n >> 4) * 6144 + (size_t)(n & 15) * 16;
    float sum = 0.f;
    for (int c8 = 0; c8 < 8; ++c8) {        // k-chunk: khalf=c8>>2, grp=c8&3
        bf16x8 hv, mv, lv;
#pragma unroll
        for (int u = 0; u < 8; ++u) {
            float v = xb[(size_t)(c8 * 8 + u) * NPTS];
            sum += v * v;
            unsigned short hb = f2bf_rne(v);
            float r1 = v - bf2f(hb);
            unsigned short mb = f2bf_rne(r1);
            float r2 = r1 - bf2f(mb);
            unsigned short lb = f2bf_rne(r2);
            hv[u] = (short)hb; mv[u] = (short)mb; lv[u] = (short)lb;
        }
        int half = c8 >> 2, grp = c8 & 3;
        size_t off = base0 + (size_t)grp * 256;
        *(bf16x8*)(xsb + off + (size_t)(0 * 2 + half) * 1024) = hv;
        *(bf16x8*)(xsb + off + (size_t)(1 * 2 + half) * 1024) = mv;
        *(bf16x8*)(xsb + off + (size_t)(2 * 2 + half) * 1024) = lv;
    }
    xx[g] = sum;
}

// ---------------------------------------------------------------------------
// Kernel B: MFMA KNN. 1-wave blocks, 32 rows/wave, NSP=2 (R6/R10 showed
// NSP=2 beats NSP=4 by ~74us: per-wave fixed costs — cutoff search, bitonic,
// A-frag loads — duplicate per split). Blocked-layout coalesced loads (R12).
// Sweep A (approx): h-only, 4-deep reg pipeline, per-lane top-2 (med3).
// Cutoff: U20_h + SLACK. Sweep B (exact): 6-product f32-exact s, 4-deep
// SB0-pinned pipeline (issue-to-use ~3 PROCB ~ 900cyc), ballot-rank appends;
// EXACT 44-bit-key bisection fallback (TRIG=32: rare; R9's 24 stormed).
// Soundness: post-compact <= 23; entering <= 31; +16 = 47 < CAP=48.
// Final: per-row bitonic (15-stage 32-wide fast path when K<=32).
// ---------------------------------------------------------------------------
#define CAP       48
#define TRIG      32
#define SLACK     2.0f

template <int NSP>
__global__ __launch_bounds__(64, 2) void knn_mfma_kernel(
    const unsigned short* __restrict__ xs, const float* __restrict__ xx,
    unsigned long long* __restrict__ ptU)
{
    const int SPLITCOLS = NPTS / NSP;
    const int NT = SPLITCOLS / 16;

    __shared__ unsigned long long bufU[32][CAP];   // 12.3 KB
    __shared__ int cntL[32];

    int lane = threadIdx.x;
    int cl = lane & 15, grp = lane >> 4;           // grp 0..3 = k-chunk of 8
    int blk = (int)blockIdx.x;
    int b = blk & 7;                    // batch -> XCD affinity
    int rt = blk >> 3;
    int n0 = (rt & 127) * 32;           // row tile within batch
    int split = rt >> 7;                // 0..NSP-1
    int c_base = split * SPLITCOLS;
    const int tbase = split * (SPLITCOLS >> 4);

    const char* XbB = (const char*)xs + (size_t)b * 1572864;
    const float* xxb = xx + ((size_t)b << 12);

    // A fragments: rows n0 + h*16 + cl
    bf16x8 aH[2][2], aM[2][2], aL[2][2];
#pragma unroll
    for (int h = 0; h < 2; ++h) {
        const char* pa = XbB + (size_t)((n0 >> 4) + h) * 6144 + lane * 16;
        aH[h][0] = *(const bf16x8*)(pa);
        aH[h][1] = *(const bf16x8*)(pa + 1024);
        aM[h][0] = *(const bf16x8*)(pa + 2048);
        aM[h][1] = *(const bf16x8*)(pa + 3072);
        aL[h][0] = *(const bf16x8*)(pa + 4096);
        aL[h][1] = *(const bf16x8*)(pa + 5120);
    }

    // ---------------- Sweep A: h-only, per-lane top-2 per row ------------
    float m1[8], m2[8];
#pragma unroll
    for (int q = 0; q < 8; ++q) { m1[q] = FLT_MAX; m2[q] = FLT_MAX; }

#define LOADH(HF_, XX_, tt) do {                                        \
        const char* p_ = XbB + (size_t)(tbase + (tt)) * 6144 + lane * 16; \
        HF_[0] = *(const bf16x8*)(p_);                                  \
        HF_[1] = *(const bf16x8*)(p_ + 1024);                           \
        XX_ = xxb[((tbase + (tt)) << 4) + cl];                          \
    } while (0)

// top-2 update: m2 <- median(m1_old, m2, s); m1 <- min(m1_old, s)
#define PROCA(HF_, XX_) do {                                            \
    f32x4 a00 = {0.f,0.f,0.f,0.f}, a01 = {0.f,0.f,0.f,0.f};             \
    f32x4 a10 = {0.f,0.f,0.f,0.f}, a11 = {0.f,0.f,0.f,0.f};             \
    a00 = MFMA(aH[0][0], HF_[0], a00);                                  \
    a10 = MFMA(aH[1][0], HF_[0], a10);                                  \
    a01 = MFMA(aH[0][1], HF_[1], a01);                                  \
    a11 = MFMA(aH[1][1], HF_[1], a11);                                  \
    _Pragma("unroll")                                                   \
    for (int j = 0; j < 4; ++j) {                                       \
      float d0 = a00[j] + a01[j], d1 = a10[j] + a11[j];                 \
      float s0 = fmaf(-2.f, d0, XX_);                                   \
      float s1 = fmaf(-2.f, d1, XX_);                                   \
      m2[j] = __builtin_amdgcn_fmed3f(m1[j], m2[j], s0);                \
      m1[j] = fminf(m1[j], s0);                                         \
      m2[4 + j] = __builtin_amdgcn_fmed3f(m1[4 + j], m2[4 + j], s1);    \
      m1[4 + j] = fminf(m1[4 + j], s1);                                 \
    }                                                                   \
} while (0)

    {
        bf16x8 h0[2], h1[2], h2[2], h3[2];
        float xa0, xa1, xa2, xa3;
        LOADH(h0, xa0, 0);
        LOADH(h1, xa1, 1);
        LOADH(h2, xa2, 2);
        for (int t = 0; t < NT; t += 4) {
            LOADH(h3, xa3, t + 3);
            SB0();
            PROCA(h0, xa0);
            if (t + 4 < NT) LOADH(h0, xa0, t + 4);
            SB0();
            PROCA(h1, xa1);
            if (t + 5 < NT) LOADH(h1, xa1, t + 5);
            SB0();
            PROCA(h2, xa2);
            if (t + 6 < NT) LOADH(h2, xa2, t + 6);
            SB0();
            PROCA(h3, xa3);
        }
    }

    // ------------- cutoff U20_h + SLACK: 16-bit-prefix binary search ----
    float cut[8];
    int   cnt[8];
    {
        unsigned long long gm = 0xFFFFull << (grp << 4);
#pragma unroll
        for (int q = 0; q < 8; ++q) {
            unsigned p1 = flip_f(m1[q]) >> 16;
            unsigned p2 = flip_f(m2[q]) >> 16;
            unsigned lo = 0, hi = 0xFFFFu;
#pragma nounroll
            for (int it = 0; it < 16; ++it) {
                unsigned mid = (lo + hi) >> 1;
                int c2 = (p1 <= mid) + (p2 <= mid);
                unsigned long long bb0 = __ballot((c2 & 1) != 0);
                unsigned long long bb1 = __ballot((c2 & 2) != 0);
                int cc = __popcll(bb0 & gm) + 2 * __popcll(bb1 & gm);
                if (cc >= KNN) hi = mid; else lo = mid + 1;
            }
            cut[q] = (hi == 0xFFFFu) ? FLT_MAX
                                     : unflip_f((hi << 16) | 0xFFFFu) + SLACK;
            cnt[q] = 0;
        }
    }
    bool needm = false;

    bf16x8 B0_[3][2], B1_[3][2], B2_[3][2], B3_[3][2];
    float xx0, xx1, xx2, xx3;

#define LOADB(BF_, XX_, tt) do {                                        \
        const char* p_ = XbB + (size_t)(tbase + (tt)) * 6144 + lane * 16; \
        BF_[0][0] = *(const bf16x8*)(p_);                               \
        BF_[0][1] = *(const bf16x8*)(p_ + 1024);                        \
        BF_[1][0] = *(const bf16x8*)(p_ + 2048);                        \
        BF_[1][1] = *(const bf16x8*)(p_ + 3072);                        \
        BF_[2][0] = *(const bf16x8*)(p_ + 4096);                        \
        BF_[2][1] = *(const bf16x8*)(p_ + 5120);                        \
        XX_ = xxb[((tbase + (tt)) << 4) + cl];                          \
    } while (0)

#define DOMFMA(B_) \
    f32x4 a00 = {0.f,0.f,0.f,0.f}, a01 = {0.f,0.f,0.f,0.f};             \
    f32x4 a10 = {0.f,0.f,0.f,0.f}, a11 = {0.f,0.f,0.f,0.f};             \
    a00 = MFMA(aH[0][0], B_[0][0], a00);                                \
    a10 = MFMA(aH[1][0], B_[0][0], a10);                                \
    a01 = MFMA(aH[0][1], B_[0][1], a01);                                \
    a11 = MFMA(aH[1][1], B_[0][1], a11);                                \
    a00 = MFMA(aM[0][0], B_[0][0], a00);                                \
    a10 = MFMA(aM[1][0], B_[0][0], a10);                                \
    a01 = MFMA(aM[0][1], B_[0][1], a01);                                \
    a11 = MFMA(aM[1][1], B_[0][1], a11);                                \
    a00 = MFMA(aH[0][0], B_[1][0], a00);                                \
    a10 = MFMA(aH[1][0], B_[1][0], a10);                                \
    a01 = MFMA(aH[0][1], B_[1][1], a01);                                \
    a11 = MFMA(aH[1][1], B_[1][1], a11);                                \
    a00 = MFMA(aM[0][0], B_[1][0], a00);                                \
    a10 = MFMA(aM[1][0], B_[1][0], a10);                                \
    a01 = MFMA(aM[0][1], B_[1][1], a01);                                \
    a11 = MFMA(aM[1][1], B_[1][1], a11);                                \
    a00 = MFMA(aL[0][0], B_[0][0], a00);                                \
    a10 = MFMA(aL[1][0], B_[0][0], a10);                                \
    a01 = MFMA(aL[0][1], B_[0][1], a01);                                \
    a11 = MFMA(aL[1][1], B_[0][1], a11);                                \
    a00 = MFMA(aH[0][0], B_[2][0], a00);                                \
    a10 = MFMA(aH[1][0], B_[2][0], a10);                                \
    a01 = MFMA(aH[0][1], B_[2][1], a01);                                \
    a11 = MFMA(aH[1][1], B_[2][1], a11);

    // ------------- fallback compaction: EXACT 44-bit-key bisection -------
#define MAINTAIN() do {                                                 \
    _Pragma("unroll")                                                   \
    for (int q = 0; q < 8; ++q) {                                       \
      if (__ballot(cnt[q] >= TRIG)) {                                   \
        bool act = (cnt[q] >= TRIG);                                    \
        int r_ = ((q >> 2) << 4) + (grp << 2) + (q & 3);                \
        if (act) {                                                      \
          int K = cnt[q];                                               \
          unsigned long long k0 = bufU[r_][cl];                         \
          unsigned long long k1 = bufU[r_][cl + 16];                    \
          unsigned long long k2 = (cl + 32 < CAP) ? bufU[r_][cl + 32] : ~0ull; \
          unsigned long long v0 = ((k0 >> 32) << 12) | (k0 & 0xFFFull); \
          unsigned long long v1 = ((k1 >> 32) << 12) | (k1 & 0xFFFull); \
          unsigned long long v2 = ((k2 >> 32) << 12) | (k2 & 0xFFFull); \
          const unsigned long long INF44 = (1ull << 44) - 1ull;         \
          if (!(cl      < K)) v0 = INF44;                               \
          if (!(cl + 16 < K)) v1 = INF44;                               \
          if (!(cl + 32 < K)) v2 = INF44;                               \
          unsigned long long gm = 0xFFFFull << (grp << 4);              \
          unsigned long long lo = 0, hi = INF44, T = INF44;             \
          _Pragma("nounroll")                                           \
          for (int it = 0; it < 46 && lo < hi; ++it) {                  \
            unsigned long long mid = lo + ((hi - lo) >> 1);             \
            int c3 = (v0 <= mid) + (v1 <= mid) + (v2 <= mid);           \
            unsigned long long bb0 = __ballot((c3 & 1) != 0);           \
            unsigned long long bb1 = __ballot((c3 & 2) != 0);           \
            int cc = __popcll(bb0 & gm) + 2 * __popcll(bb1 & gm);       \
            if (cc >= KNN && cc <= 23) { T = mid; break; }              \
            if (cc < KNN) lo = mid + 1; else { hi = mid; T = mid; }     \
          }                                                             \
          bool p0 = (v0 <= T);                                          \
          bool p1 = (v1 <= T);                                          \
          bool p2 = (v2 <= T);                                          \
          unsigned long long bq_;                                       \
          bq_ = __ballot(p0); unsigned m0_ = (unsigned)((bq_ >> (grp << 4)) & 0xFFFFull); \
          bq_ = __ballot(p1); unsigned m1_ = (unsigned)((bq_ >> (grp << 4)) & 0xFFFFull); \
          bq_ = __ballot(p2); unsigned m2_ = (unsigned)((bq_ >> (grp << 4)) & 0xFFFFull); \
          int base1 = __popc(m0_), base2 = base1 + __popc(m1_);         \
          int newK = base2 + __popc(m2_);                               \
          unsigned below = (1u << cl) - 1u;                             \
          if (p0) bufU[r_][__popc(m0_ & below)] = k0;                   \
          if (p1) bufU[r_][base1 + __popc(m1_ & below)] = k1;           \
          if (p2) bufU[r_][base2 + __popc(m2_ & below)] = k2;           \
          cnt[q] = newK;                                                \
          cut[q] = unflip_f((unsigned)(T >> 12));                       \
        }                                                               \
      }                                                                 \
    }                                                                   \
} while (0)

    // ---------------- Sweep B: append s <= cut ---------------------------
#define PROCB(B_, XX_, MCOL_) do {                                      \
    DOMFMA(B_)                                                          \
    float s_[8]; bool p_[8];                                            \
    _Pragma("unroll")                                                   \
    for (int j = 0; j < 4; ++j) {                                       \
      float d0 = a00[j] + a01[j], d1 = a10[j] + a11[j];                 \
      s_[j]     = fmaf(-2.f, d0, XX_); p_[j]     = (s_[j]     <= cut[j]);     \
      s_[4 + j] = fmaf(-2.f, d1, XX_); p_[4 + j] = (s_[4 + j] <= cut[4 + j]); \
    }                                                                   \
    bool anyp = p_[0]|p_[1]|p_[2]|p_[3]|p_[4]|p_[5]|p_[6]|p_[7];        \
    if (__ballot(anyp)) {                                               \
      _Pragma("unroll")                                                 \
      for (int q = 0; q < 8; ++q) {                                     \
        unsigned long long bq = __ballot(p_[q]);                        \
        unsigned mq = (unsigned)((bq >> (grp << 4)) & 0xFFFFull);       \
        if (mq) {                                                       \
          int r_ = ((q >> 2) << 4) + (grp << 2) + (q & 3);              \
          int pos = cnt[q] + __popc(mq & ((1u << cl) - 1u));            \
          if (p_[q]) { if (pos >= CAP) pos = CAP - 1;                   \
                       bufU[r_][pos] = pack_key(s_[q], (MCOL_)); }      \
          cnt[q] += __popc(mq);                                         \
          needm |= (cnt[q] >= TRIG);                                    \
        }                                                               \
      }                                                                 \
      if (__ballot(needm)) { MAINTAIN(); needm = false; }               \
    }                                                                   \
} while (0)

    LOADB(B0_, xx0, 0);
    LOADB(B1_, xx1, 1);
    LOADB(B2_, xx2, 2);
    for (int t = 0; t < NT; t += 4) {
        LOADB(B3_, xx3, t + 3);
        SB0();
        PROCB(B0_, xx0, c_base + t * 16 + cl);
        if (t + 4 < NT) LOADB(B0_, xx0, t + 4);
        SB0();
        PROCB(B1_, xx1, c_base + (t + 1) * 16 + cl);
        if (t + 5 < NT) LOADB(B1_, xx1, t + 5);
        SB0();
        PROCB(B2_, xx2, c_base + (t + 2) * 16 + cl);
        if (t + 6 < NT) LOADB(B2_, xx2, t + 6);
        SB0();
        PROCB(B3_, xx3, c_base + (t + 3) * 16 + cl);
    }

    // publish per-row counts
#pragma unroll
    for (int q = 0; q < 8; ++q)
        if (cl == 0) cntL[((q >> 2) << 4) + (grp << 2) + (q & 3)] = cnt[q];
    __syncthreads();

    // final exact per-row top-20 bitonic; K<=32 fast path (15 vs 21 stages)
#pragma nounroll
    for (int r = 0; r < 32; ++r) {
        int K = cntL[r];
        if (K > CAP) K = CAP;
        unsigned long long v = (lane < K) ? bufU[r][lane] : ~0ull;
        if (K <= 32) {
#pragma unroll
            for (int k = 2; k <= 32; k <<= 1) {
#pragma unroll
                for (int j = k >> 1; j > 0; j >>= 1) {
                    unsigned long long o = __shfl_xor(v, j);
                    bool takeMin = (((lane & j) == 0) == ((lane & k) == 0));
                    v = ((v <= o) == takeMin) ? v : o;
                }
            }
        } else {
#pragma unroll
            for (int k = 2; k <= 64; k <<= 1) {
#pragma unroll
                for (int j = k >> 1; j > 0; j >>= 1) {
                    unsigned long long o = __shfl_xor(v, j);
                    bool takeMin = (((lane & j) == 0) == ((lane & k) == 0));
                    v = ((v <= o) == takeMin) ? v : o;
                }
            }
        }
        if (lane < KNN)
            ptU[((size_t)split * (NB * NPTS) + ((size_t)b << 12) + (n0 + r)) * KNN + lane] = v;
    }
#undef LOADH
#undef PROCA
#undef LOADB
#undef DOMFMA
#undef MAINTAIN
#undef PROCB
}

// ---------------------------------------------------------------------------
// Kernel M: merge the NSP sorted top-20 lists per row -> final idx.
// ---------------------------------------------------------------------------
template <int NSP>
__global__ void merge_kernel(const unsigned long long* __restrict__ ptU,
                             int* __restrict__ idxout)
{
    int row = blockIdx.x * 256 + threadIdx.x;
    const unsigned long long* L[NSP];
    int p[NSP];
#pragma unroll
    for (int s = 0; s < NSP; ++s) {
        L[s] = ptU + ((size_t)s * (NB * NPTS) + row) * KNN;
        p[s] = 0;
    }
    for (int j = 0; j < KNN; ++j) {
        unsigned long long best = ~0ull; int bs = 0;
#pragma unroll
        for (int s = 0; s < NSP; ++s) {
            unsigned long long k = (p[s] < KNN) ? L[s][p[s]] : ~0ull;
            if (k < best) { best = k; bs = s; }
        }
        ++p[bs];
        idxout[(size_t)row * KNN + j] = (int)(best & 0xffffffffu);
    }
}

// ---------------------------------------------------------------------------
// Kernel A2: per-point y1 = W1*x, y2 = (W2-W1)*x
// ---------------------------------------------------------------------------
__global__ __launch_bounds__(256, 2) void precompute_kernel(
    const float* __restrict__ x, const float* __restrict__ W,
    float* __restrict__ y1, float* __restrict__ y2)
{
    __shared__ float4 wf4[64 * 32];
    int t = threadIdx.x;
    for (int i = 0; i < 8; ++i) {
        int e = t + 256 * i;
        wf4[e] = ((const float4*)W)[e];
    }
    int p = t & 63, og = t >> 6;
    int g = blockIdx.x * 64 + p;
    int b = g >> 12, n = g & 4095;
    const float* xb = x + (size_t)b * NC * NPTS + n;

    float4 xr[16];
#pragma unroll
    for (int c4 = 0; c4 < 16; ++c4) {
        xr[c4].x = xb[(4 * c4 + 0) * NPTS];
        xr[c4].y = xb[(4 * c4 + 1) * NPTS];
        xr[c4].z = xb[(4 * c4 + 2) * NPTS];
        xr[c4].w = xb[(4 * c4 + 3) * NPTS];
    }
    __syncthreads();

    float out1[16], out2[16];
#pragma unroll
    for (int oi = 0; oi < 16; ++oi) {
        int o = og * 16 + oi;
        float a1 = 0.f, a2 = 0.f;
#pragma unroll
        for (int c4 = 0; c4 < 16; ++c4) {
            float4 w1 = wf4[o * 32 + c4];
            float4 w2 = wf4[o * 32 + 16 + c4];
            float4 xv = xr[c4];
            a1 += w1.x * xv.x + w1.y * xv.y + w1.z * xv.z + w1.w * xv.w;
            a2 += w2.x * xv.x + w2.y * xv.y + w2.z * xv.z + w2.w * xv.w;
        }
        out1[oi] = a1;
        out2[oi] = a2 - a1;
    }
    float4* y1p = (float4*)(y1 + (size_t)g * 64 + og * 16);
    float4* y2p = (float4*)(y2 + (size_t)g * 64 + og * 16);
#pragma unroll
    for (int q = 0; q < 4; ++q) {
        y1p[q] = make_float4(out1[4*q], out1[4*q+1], out1[4*q+2], out1[4*q+3]);
        y2p[q] = make_float4(out2[4*q], out2[4*q+1], out2[4*q+2], out2[4*q+3]);
    }
}

// ---------------------------------------------------------------------------
// Kernel C: per-channel sum/sumsq of v = y1[idx]+y2; optionally also emits
// per-(point,o) vmax/vmin planes so the epilogue can stream.
// ---------------------------------------------------------------------------
__global__ __launch_bounds__(256, 4) void stats_kernel(
    const float* __restrict__ y1, const float* __restrict__ y2,
    const int* __restrict__ idx, float* __restrict__ part,
    float* __restrict__ mmax, float* __restrict__ mmin)
{
    int t = threadIdx.x;
    int o = t & 63, p4 = t >> 6;
    int blk = (int)blockIdx.x;
    int g0 = ((blk & 7) * 64 + (blk >> 3)) * 64;
    float s1 = 0.f, s2 = 0.f;
    for (int pi = 0; pi < 16; ++pi) {
        int g = g0 + pi * 4 + p4;
        int b = g >> 12;
        float y2v = y2[(size_t)g * 64 + o];
        const int* ip = idx + (size_t)g * KNN;
        float vmax = -FLT_MAX, vmin = FLT_MAX;
#pragma unroll
        for (int j = 0; j < KNN; ++j) {
            int id = ip[j];
            float v = y1[((size_t)(b << 12) + id) * 64 + o] + y2v;
            s1 += v; s2 += v * v;
            vmax = fmaxf(vmax, v); vmin = fminf(vmin, v);
        }
        if (mmax) {
            mmax[(size_t)g * 64 + o] = vmax;
            mmin[(size_t)g * 64 + o] = vmin;
        }
    }
    __shared__ float red[256];
    red[t] = s1; __syncthreads();
    if (t < 64) part[blockIdx.x * 128 + o] = red[o] + red[64 + o] + red[128 + o] + red[192 + o];
    __syncthreads();
    red[t] = s2; __syncthreads();
    if (t < 64) part[blockIdx.x * 128 + 64 + o] = red[o] + red[64 + o] + red[128 + o] + red[192 + o];
}

__global__ void finalize_stats_kernel(
    const float* __restrict__ part, const float* __restrict__ gamma,
    const float* __restrict__ beta, float* __restrict__ ss)
{
    int t = threadIdx.x;   // 128 threads
    float S = 0.f;
    for (int p = 0; p < 512; ++p) S += part[p * 128 + t];
    __shared__ float sm[128];
    sm[t] = S; __syncthreads();
    if (t < 64) {
        const float inv = 1.f / (float)(NB * NPTS * KNN);
        float mean = sm[t] * inv;
        float var  = sm[64 + t] * inv - mean * mean;
        float scale = gamma[t] * rsqrtf(var + 1e-5f);
        ss[t] = scale;
        ss[64 + t] = beta[t] - mean * scale;
    }
}

// ---------------------------------------------------------------------------
// Kernel E (streaming): affine+relu from minmax planes, transpose, write.
// ---------------------------------------------------------------------------
__global__ __launch_bounds__(256, 4) void epilogue_stream_kernel(
    const float* __restrict__ mmax, const float* __restrict__ mmin,
    const float* __restrict__ ss, float* __restrict__ out)
{
    __shared__ float zT[64][65];
    int t = threadIdx.x;
    int o = t & 63, p4 = t >> 6;
    float sc = ss[o], sh = ss[64 + o];
    int blk = (int)blockIdx.x;
    int g0 = ((blk & 7) * 64 + (blk >> 3)) * 64;
    int b = g0 >> 12, n0 = g0 & 4095;
    for (int pi = 0; pi < 16; ++pi) {
        int pc = pi * 4 + p4;
        int g = g0 + pc;
        float vmax = mmax[(size_t)g * 64 + o];
        float vmin = mmin[(size_t)g * 64 + o];
        float z = (sc >= 0.f) ? sc * vmax + sh : sc * vmin + sh;
        zT[o][pc] = fmaxf(z, 0.f);
    }
    __syncthreads();
    for (int i = 0; i < 16; ++i) {
        int e = t + 256 * i;
        int oo = e >> 6, nn = e & 63;
        out[((size_t)(b * 64 + oo)) * 4096 + n0 + nn] = zT[oo][nn];
    }
}

// Kernel E (gather fallback, small-ws path)
__global__ __launch_bounds__(256, 4) void epilogue_gather_kernel(
    const float* __restrict__ y1, const float* __restrict__ y2,
    const int* __restrict__ idx, const float* __restrict__ ss,
    float* __restrict__ out)
{
    __shared__ float zT[64][65];
    int t = threadIdx.x;
    int o = t & 63, p4 = t >> 6;
    float sc = ss[o], sh = ss[64 + o];
    int blk = (int)blockIdx.x;
    int g0 = ((blk & 7) * 64 + (blk >> 3)) * 64;
    int b = g0 >> 12, n0 = g0 & 4095;
    for (int pi = 0; pi < 16; ++pi) {
        int pc = pi * 4 + p4;
        int g = g0 + pc;
        float y2v = y2[(size_t)g * 64 + o];
        const int* ip = idx + (size_t)g * KNN;
        float vmax = -FLT_MAX, vmin = FLT_MAX;
#pragma unroll
        for (int j = 0; j < KNN; ++j) {
            int id = ip[j];
            float v = y1[((size_t)(b << 12) + id) * 64 + o] + y2v;
            vmax = fmaxf(vmax, v); vmin = fminf(vmin, v);
        }
        float z = (sc >= 0.f) ? sc * vmax + sh : sc * vmin + sh;
        zT[o][pc] = fmaxf(z, 0.f);
    }
    __syncthreads();
    for (int i = 0; i < 16; ++i) {
        int e = t + 256 * i;
        int oo = e >> 6, nn = e & 63;
        out[((size_t)(b * 64 + oo)) * 4096 + n0 + nn] = zT[oo][nn];
    }
}

// ---------------------------------------------------------------------------
extern "C" void kernel_launch(void* const* d_in, const int* in_sizes, int n_in,
                              void* d_out, int out_size, void* d_ws, size_t ws_size,
                              hipStream_t stream)
{
    const float* x     = (const float*)d_in[0];
    const float* W     = (const float*)d_in[1];
    const float* gamma = (const float*)d_in[2];
    const float* beta  = (const float*)d_in[3];
    float* out = (float*)d_out;

    char* ws = (char*)d_ws;
    unsigned short* xs = (unsigned short*)(ws);                     // 12 MB
    unsigned long long* ptU = (unsigned long long*)(ws + 12582912); // 10.49 MB (NSP=2)

    // "big" layout keeps the old 4-split-sized ptU shadow so mmax/mmin can
    // overlay dead space; gate identical to previous rounds (~36.6 MB).
    const size_t need4 = 12582912ull + 20971520ull + 2621440ull + 131072ull
                       + 262144ull + 512ull;
    const bool big = (ws_size >= need4);
    const size_t tail_off = big ? (12582912ull + 20971520ull)       // 33.55 MB
                                : (12582912ull + 10485760ull);      // 23.07 MB

    char* tail = ws + tail_off;
    int*   idx  = (int*)  (tail);
    float* xx   = (float*)(tail + 2621440);
    float* part = (float*)(tail + 2621440 + 131072);
    float* ss   = (float*)(tail + 2621440 + 131072 + 262144);
    // phase 2 overlays the dead xs+ptU region
    float* y1   = (float*)(ws);                                     // 8 MB
    float* y2   = (float*)(ws + 8388608);                           // 8 MB
    float* mmax = (float*)(ws + 16777216);                          // 8 MB (big only)
    float* mmin = (float*)(ws + 25165824);                          // 8 MB (big only)

    hipLaunchKernelGGL(split_kernel, dim3(128), dim3(256), 0, stream, x, xs, xx);
    hipLaunchKernelGGL((knn_mfma_kernel<2>), dim3(2048), dim3(64), 0, stream, xs, xx, ptU);
    hipLaunchKernelGGL((merge_kernel<2>),    dim3(128),  dim3(256), 0, stream, ptU, idx);
    hipLaunchKernelGGL(precompute_kernel, dim3(512), dim3(256), 0, stream, x, W, y1, y2);
    if (big) {
        hipLaunchKernelGGL(stats_kernel,          dim3(512), dim3(256), 0, stream, y1, y2, idx, part, mmax, mmin);
        hipLaunchKernelGGL(finalize_stats_kernel, dim3(1),   dim3(128), 0, stream, part, gamma, beta, ss);
        hipLaunchKernelGGL(epilogue_stream_kernel, dim3(512), dim3(256), 0, stream, mmax, mmin, ss, out);
    } else {
        hipLaunchKernelGGL(stats_kernel,          dim3(512), dim3(256), 0, stream, y1, y2, idx, part, (float*)nullptr, (float*)nullptr);
        hipLaunchKernelGGL(finalize_stats_kernel, dim3(1),   dim3(128), 0, stream, part, gamma, beta, ss);
        hipLaunchKernelGGL(epilogue_gather_kernel, dim3(512), dim3(256), 0, stream, y1, y2, idx, ss, out);
    }
}

// Round 14
// 307.616 us; speedup vs baseline: 1.8055x; 1.1417x over previous
//
#include <hip/hip_runtime.h>
#include <cfloat>

#define NB   8
#define NC   64
#define NPTS 4096
#define KNN  20
#define CO   64

typedef __attribute__((ext_vector_type(8))) short bf16x8;
typedef __attribute__((ext_vector_type(4))) float f32x4;

#define MFMA(a, b, c) __builtin_amdgcn_mfma_f32_16x16x32_bf16(a, b, c, 0, 0, 0)
#define SB0() __builtin_amdgcn_sched_barrier(0)

// ---------------------------------------------------------------------------
// bf16 helpers (RNE, bit-level; no NaN in this workload)
// ---------------------------------------------------------------------------
__device__ __forceinline__ unsigned short f2bf_rne(float f) {
    unsigned int u = __float_as_uint(f);
    unsigned int r = (u + 0x7FFFu + ((u >> 16) & 1u)) >> 16;
    return (unsigned short)r;
}
__device__ __forceinline__ float bf2f(unsigned short h) {
    return __uint_as_float(((unsigned int)h) << 16);
}
__device__ __forceinline__ unsigned int flip_f(float s) {
    unsigned int b = __float_as_uint(s);
    return (b & 0x80000000u) ? ~b : (b | 0x80000000u);
}
__device__ __forceinline__ float unflip_f(unsigned int u) {
    unsigned int b = (u & 0x80000000u) ? (u ^ 0x80000000u) : ~u;
    return __uint_as_float(b);
}
__device__ __forceinline__ unsigned long long pack_key(float s, int m) {
    return (((unsigned long long)flip_f(s)) << 32) | (unsigned int)m;
}

// ---------------------------------------------------------------------------
// BLOCKED xs layout (R12): per batch, 256 tiles of 16 points.
// addr(tile, fg, grp, cl) = tile*6144 + fg*1024 + grp*256 + cl*16,
// fg = f*2 + khalf (f: 0=h,1=m,2=l). 64-lane fragment load = base+lane*16.
// x = h+m+l+eps, |eps|<=2^-27|x|.
// ---------------------------------------------------------------------------
__global__ __launch_bounds__(256, 4) void split_kernel(
    const float* __restrict__ x, unsigned short* __restrict__ xs,
    float* __restrict__ xx)
{
    int g = blockIdx.x * 256 + threadIdx.x;
    int b = g >> 12, n = g & 4095;
    const float* xb = x + ((size_t)b << 18) + n;
    char* xsb = (char*)xs;
    size_t base0 = (size_t)b * 1572864 + (size_t)(n >> 4) * 6144 + (size_t)(n & 15) * 16;
    float sum = 0.f;
    for (int c8 = 0; c8 < 8; ++c8) {        // khalf=c8>>2, grp=c8&3
        bf16x8 hv, mv, lv;
#pragma unroll
        for (int u = 0; u < 8; ++u) {
            float v = xb[(size_t)(c8 * 8 + u) * NPTS];
            sum += v * v;
            unsigned short hb = f2bf_rne(v);
            float r1 = v - bf2f(hb);
            unsigned short mb = f2bf_rne(r1);
            float r2 = r1 - bf2f(mb);
            unsigned short lb = f2bf_rne(r2);
            hv[u] = (short)hb; mv[u] = (short)mb; lv[u] = (short)lb;
        }
        int half = c8 >> 2, grp = c8 & 3;
        size_t off = base0 + (size_t)grp * 256;
        *(bf16x8*)(xsb + off + (size_t)(0 * 2 + half) * 1024) = hv;
        *(bf16x8*)(xsb + off + (size_t)(1 * 2 + half) * 1024) = mv;
        *(bf16x8*)(xsb + off + (size_t)(2 * 2 + half) * 1024) = lv;
    }
    xx[g] = sum;
}

// ---------------------------------------------------------------------------
// Kernel B: MFMA KNN. 2048 blocks x 2 INDEPENDENT waves x 16 rows each
// (same 32 rows/block and same total VALU as R13, but 16 waves/CU instead
// of 8 — the grid was the binding occupancy limit; R11's 2-wave failure
// predated the coalesced blocked layout). Zero barriers: LDS partitioned
// by wid, DS ops in-order per wave. One 16x16 A-tile per wave; 2
// independent 6-MFMA accumulator chains (by k-half). NSP=2 column splits.
// Sweep A (approx): h-only, 4-deep pipeline, per-lane top-2 (med3).
// Cutoff: U20_h + SLACK (|s_e - s_h| <= 2*sqrt(xx_n xx_m)*2^-8 < 2.0).
// Sweep B (exact): 6-product f32-exact s, 2-deep SB0 pipeline, ballot-rank
// appends; EXACT 44-bit-key bisection fallback (TRIG=32: rare).
// Soundness: post-compact <= 23; entering <= 31; +16 = 47 < CAP=48.
// Final: per-row bitonic (32-wide fast path when K<=32).
// ---------------------------------------------------------------------------
#define CAP       48
#define TRIG      32
#define SLACK     2.0f

template <int NSP>
__global__ __launch_bounds__(128, 2) void knn_mfma_kernel(
    const unsigned short* __restrict__ xs, const float* __restrict__ xx,
    unsigned long long* __restrict__ ptU)
{
    const int SPLITCOLS = NPTS / NSP;
    const int NT = SPLITCOLS / 16;

    __shared__ unsigned long long bufU[32][CAP];   // 12.3 KB, wid-partitioned
    __shared__ int cntL[32];

    int tid = threadIdx.x;
    int lane = tid & 63, wid = tid >> 6;           // 2 independent waves
    int cl = lane & 15, grp = lane >> 4;
    int blk = (int)blockIdx.x;
    int b = blk & 7;                    // batch -> XCD affinity
    int rt = blk >> 3;
    int rowtile = rt & 127;             // 128 x 32-row tiles per batch
    int split = rt >> 7;                // 0..NSP-1
    int n0 = rowtile * 32 + wid * 16;   // this wave's 16 rows
    int c_base = split * SPLITCOLS;
    const int tbase = split * (SPLITCOLS >> 4);

    const char* XbB = (const char*)xs + (size_t)b * 1572864;
    const float* xxb = xx + ((size_t)b << 12);

    // A fragments: one 16-row tile, k-halves 0/1
    bf16x8 aH[2], aM[2], aL[2];
    {
        const char* pa = XbB + (size_t)(rowtile * 2 + wid) * 6144 + lane * 16;
        aH[0] = *(const bf16x8*)(pa);
        aH[1] = *(const bf16x8*)(pa + 1024);
        aM[0] = *(const bf16x8*)(pa + 2048);
        aM[1] = *(const bf16x8*)(pa + 3072);
        aL[0] = *(const bf16x8*)(pa + 4096);
        aL[1] = *(const bf16x8*)(pa + 5120);
    }

    // ---------------- Sweep A: h-only, per-lane top-2 per row ------------
    float m1[4], m2[4];
#pragma unroll
    for (int q = 0; q < 4; ++q) { m1[q] = FLT_MAX; m2[q] = FLT_MAX; }

#define LOADH(HF_, XX_, tt) do {                                        \
        const char* p_ = XbB + (size_t)(tbase + (tt)) * 6144 + lane * 16; \
        HF_[0] = *(const bf16x8*)(p_);                                  \
        HF_[1] = *(const bf16x8*)(p_ + 1024);                           \
        XX_ = xxb[((tbase + (tt)) << 4) + cl];                          \
    } while (0)

#define PROCA(HF_, XX_) do {                                            \
    f32x4 a0 = {0.f,0.f,0.f,0.f}, a1 = {0.f,0.f,0.f,0.f};               \
    a0 = MFMA(aH[0], HF_[0], a0);                                       \
    a1 = MFMA(aH[1], HF_[1], a1);                                       \
    _Pragma("unroll")                                                   \
    for (int j = 0; j < 4; ++j) {                                       \
      float s0 = fmaf(-2.f, a0[j] + a1[j], XX_);                        \
      m2[j] = __builtin_amdgcn_fmed3f(m1[j], m2[j], s0);                \
      m1[j] = fminf(m1[j], s0);                                         \
    }                                                                   \
} while (0)

    {
        bf16x8 h0[2], h1[2], h2[2], h3[2];
        float xa0, xa1, xa2, xa3;
        LOADH(h0, xa0, 0);
        LOADH(h1, xa1, 1);
        LOADH(h2, xa2, 2);
        for (int t = 0; t < NT; t += 4) {
            LOADH(h3, xa3, t + 3);
            SB0();
            PROCA(h0, xa0);
            if (t + 4 < NT) LOADH(h0, xa0, t + 4);
            SB0();
            PROCA(h1, xa1);
            if (t + 5 < NT) LOADH(h1, xa1, t + 5);
            SB0();
            PROCA(h2, xa2);
            if (t + 6 < NT) LOADH(h2, xa2, t + 6);
            SB0();
            PROCA(h3, xa3);
        }
    }

    // ------------- cutoff U20_h + SLACK: 16-bit-prefix binary search ----
    float cut[4];
    int   cnt[4];
    {
        unsigned long long gm = 0xFFFFull << (grp << 4);
#pragma unroll
        for (int q = 0; q < 4; ++q) {
            unsigned p1 = flip_f(m1[q]) >> 16;
            unsigned p2 = flip_f(m2[q]) >> 16;
            unsigned lo = 0, hi = 0xFFFFu;
#pragma nounroll
            for (int it = 0; it < 16; ++it) {
                unsigned mid = (lo + hi) >> 1;
                int c2 = (p1 <= mid) + (p2 <= mid);
                unsigned long long bb0 = __ballot((c2 & 1) != 0);
                unsigned long long bb1 = __ballot((c2 & 2) != 0);
                int cc = __popcll(bb0 & gm) + 2 * __popcll(bb1 & gm);
                if (cc >= KNN) hi = mid; else lo = mid + 1;
            }
            cut[q] = (hi == 0xFFFFu) ? FLT_MAX
                                     : unflip_f((hi << 16) | 0xFFFFu) + SLACK;
            cnt[q] = 0;
        }
    }
    bool needm = false;

    bf16x8 B0_[3][2], B1_[3][2];
    float xx0, xx1;

#define LOADB(BF_, XX_, tt) do {                                        \
        const char* p_ = XbB + (size_t)(tbase + (tt)) * 6144 + lane * 16; \
        BF_[0][0] = *(const bf16x8*)(p_);                               \
        BF_[0][1] = *(const bf16x8*)(p_ + 1024);                        \
        BF_[1][0] = *(const bf16x8*)(p_ + 2048);                        \
        BF_[1][1] = *(const bf16x8*)(p_ + 3072);                        \
        BF_[2][0] = *(const bf16x8*)(p_ + 4096);                        \
        BF_[2][1] = *(const bf16x8*)(p_ + 5120);                        \
        XX_ = xxb[((tbase + (tt)) << 4) + cl];                          \
    } while (0)

// two independent 6-MFMA chains (k-half 0 / 1)
#define DOMFMA(B_) \
    f32x4 a0 = {0.f,0.f,0.f,0.f}, a1 = {0.f,0.f,0.f,0.f};               \
    a0 = MFMA(aH[0], B_[0][0], a0);                                     \
    a1 = MFMA(aH[1], B_[0][1], a1);                                     \
    a0 = MFMA(aM[0], B_[0][0], a0);                                     \
    a1 = MFMA(aM[1], B_[0][1], a1);                                     \
    a0 = MFMA(aH[0], B_[1][0], a0);                                     \
    a1 = MFMA(aH[1], B_[1][1], a1);                                     \
    a0 = MFMA(aM[0], B_[1][0], a0);                                     \
    a1 = MFMA(aM[1], B_[1][1], a1);                                     \
    a0 = MFMA(aL[0], B_[0][0], a0);                                     \
    a1 = MFMA(aL[1], B_[0][1], a1);                                     \
    a0 = MFMA(aH[0], B_[2][0], a0);                                     \
    a1 = MFMA(aH[1], B_[2][1], a1);

    // ------------- fallback compaction: EXACT 44-bit-key bisection -------
#define MAINTAIN() do {                                                 \
    _Pragma("unroll")                                                   \
    for (int q = 0; q < 4; ++q) {                                       \
      if (__ballot(cnt[q] >= TRIG)) {                                   \
        bool act = (cnt[q] >= TRIG);                                    \
        int r_ = (wid << 4) + (grp << 2) + q;                           \
        if (act) {                                                      \
          int K = cnt[q];                                               \
          unsigned long long k0 = bufU[r_][cl];                         \
          unsigned long long k1 = bufU[r_][cl + 16];                    \
          unsigned long long k2 = (cl + 32 < CAP) ? bufU[r_][cl + 32] : ~0ull; \
          unsigned long long v0 = ((k0 >> 32) << 12) | (k0 & 0xFFFull); \
          unsigned long long v1 = ((k1 >> 32) << 12) | (k1 & 0xFFFull); \
          unsigned long long v2 = ((k2 >> 32) << 12) | (k2 & 0xFFFull); \
          const unsigned long long INF44 = (1ull << 44) - 1ull;         \
          if (!(cl      < K)) v0 = INF44;                               \
          if (!(cl + 16 < K)) v1 = INF44;                               \
          if (!(cl + 32 < K)) v2 = INF44;                               \
          unsigned long long gm = 0xFFFFull << (grp << 4);              \
          unsigned long long lo = 0, hi = INF44, T = INF44;             \
          _Pragma("nounroll")                                           \
          for (int it = 0; it < 46 && lo < hi; ++it) {                  \
            unsigned long long mid = lo + ((hi - lo) >> 1);             \
            int c3 = (v0 <= mid) + (v1 <= mid) + (v2 <= mid);           \
            unsigned long long bb0 = __ballot((c3 & 1) != 0);           \
            unsigned long long bb1 = __ballot((c3 & 2) != 0);           \
            int cc = __popcll(bb0 & gm) + 2 * __popcll(bb1 & gm);       \
            if (cc >= KNN && cc <= 23) { T = mid; break; }              \
            if (cc < KNN) lo = mid + 1; else { hi = mid; T = mid; }     \
          }                                                             \
          bool p0 = (v0 <= T);                                          \
          bool p1 = (v1 <= T);                                          \
          bool p2 = (v2 <= T);                                          \
          unsigned long long bq_;                                       \
          bq_ = __ballot(p0); unsigned m0_ = (unsigned)((bq_ >> (grp << 4)) & 0xFFFFull); \
          bq_ = __ballot(p1); unsigned m1_ = (unsigned)((bq_ >> (grp << 4)) & 0xFFFFull); \
          bq_ = __ballot(p2); unsigned m2_ = (unsigned)((bq_ >> (grp << 4)) & 0xFFFFull); \
          int base1 = __popc(m0_), base2 = base1 + __popc(m1_);         \
          int newK = base2 + __popc(m2_);                               \
          unsigned below = (1u << cl) - 1u;                             \
          if (p0) bufU[r_][__popc(m0_ & below)] = k0;                   \
          if (p1) bufU[r_][base1 + __popc(m1_ & below)] = k1;           \
          if (p2) bufU[r_][base2 + __popc(m2_ & below)] = k2;           \
          cnt[q] = newK;                                                \
          cut[q] = unflip_f((unsigned)(T >> 12));                       \
        }                                                               \
      }                                                                 \
    }                                                                   \
} while (0)

    // ---------------- Sweep B: append s <= cut ---------------------------
#define PROCB(B_, XX_, MCOL_) do {                                      \
    DOMFMA(B_)                                                          \
    float s_[4]; bool p_[4];                                            \
    _Pragma("unroll")                                                   \
    for (int j = 0; j < 4; ++j) {                                       \
      s_[j] = fmaf(-2.f, a0[j] + a1[j], XX_);                           \
      p_[j] = (s_[j] <= cut[j]);                                        \
    }                                                                   \
    bool anyp = p_[0] | p_[1] | p_[2] | p_[3];                          \
    if (__ballot(anyp)) {                                               \
      _Pragma("unroll")                                                 \
      for (int q = 0; q < 4; ++q) {                                     \
        unsigned long long bq = __ballot(p_[q]);                        \
        unsigned mq = (unsigned)((bq >> (grp << 4)) & 0xFFFFull);       \
        if (mq) {                                                       \
          int r_ = (wid << 4) + (grp << 2) + q;                         \
          int pos = cnt[q] + __popc(mq & ((1u << cl) - 1u));            \
          if (p_[q]) { if (pos >= CAP) pos = CAP - 1;                   \
                       bufU[r_][pos] = pack_key(s_[q], (MCOL_)); }      \
          cnt[q] += __popc(mq);                                         \
          needm |= (cnt[q] >= TRIG);                                    \
        }                                                               \
      }                                                                 \
      if (__ballot(needm)) { MAINTAIN(); needm = false; }               \
    }                                                                   \
} while (0)

    LOADB(B0_, xx0, 0);
    for (int t = 0; t < NT; t += 2) {
        LOADB(B1_, xx1, t + 1);
        SB0();
        PROCB(B0_, xx0, c_base + t * 16 + cl);
        if (t + 2 < NT) LOADB(B0_, xx0, t + 2);
        SB0();
        PROCB(B1_, xx1, c_base + (t + 1) * 16 + cl);
    }

    // publish per-row counts (intra-wave LDS, wid-partitioned: no barrier)
#pragma unroll
    for (int q = 0; q < 4; ++q)
        if (cl == 0) cntL[(wid << 4) + (grp << 2) + q] = cnt[q];

    // final exact per-row top-20 bitonic; K<=32 fast path
#pragma nounroll
    for (int r = 0; r < 16; ++r) {
        int lrow = (wid << 4) + r;
        int K = cntL[lrow];
        if (K > CAP) K = CAP;
        unsigned long long v = (lane < K) ? bufU[lrow][lane] : ~0ull;
        if (K <= 32) {
#pragma unroll
            for (int k = 2; k <= 32; k <<= 1) {
#pragma unroll
                for (int j = k >> 1; j > 0; j >>= 1) {
                    unsigned long long o = __shfl_xor(v, j);
                    bool takeMin = (((lane & j) == 0) == ((lane & k) == 0));
                    v = ((v <= o) == takeMin) ? v : o;
                }
            }
        } else {
#pragma unroll
            for (int k = 2; k <= 64; k <<= 1) {
#pragma unroll
                for (int j = k >> 1; j > 0; j >>= 1) {
                    unsigned long long o = __shfl_xor(v, j);
                    bool takeMin = (((lane & j) == 0) == ((lane & k) == 0));
                    v = ((v <= o) == takeMin) ? v : o;
                }
            }
        }
        if (lane < KNN)
            ptU[((size_t)split * (NB * NPTS) + ((size_t)b << 12) + (n0 + r)) * KNN + lane] = v;
    }
#undef LOADH
#undef PROCA
#undef LOADB
#undef DOMFMA
#undef MAINTAIN
#undef PROCB
}

// ---------------------------------------------------------------------------
// Kernel M: merge the NSP sorted top-20 lists per row -> final idx.
// ---------------------------------------------------------------------------
template <int NSP>
__global__ void merge_kernel(const unsigned long long* __restrict__ ptU,
                             int* __restrict__ idxout)
{
    int row = blockIdx.x * 256 + threadIdx.x;
    const unsigned long long* L[NSP];
    int p[NSP];
#pragma unroll
    for (int s = 0; s < NSP; ++s) {
        L[s] = ptU + ((size_t)s * (NB * NPTS) + row) * KNN;
        p[s] = 0;
    }
    for (int j = 0; j < KNN; ++j) {
        unsigned long long best = ~0ull; int bs = 0;
#pragma unroll
        for (int s = 0; s < NSP; ++s) {
            unsigned long long k = (p[s] < KNN) ? L[s][p[s]] : ~0ull;
            if (k < best) { best = k; bs = s; }
        }
        ++p[bs];
        idxout[(size_t)row * KNN + j] = (int)(best & 0xffffffffu);
    }
}

// ---------------------------------------------------------------------------
// Kernel A2: per-point y1 = W1*x, y2 = (W2-W1)*x
// ---------------------------------------------------------------------------
__global__ __launch_bounds__(256, 2) void precompute_kernel(
    const float* __restrict__ x, const float* __restrict__ W,
    float* __restrict__ y1, float* __restrict__ y2)
{
    __shared__ float4 wf4[64 * 32];
    int t = threadIdx.x;
    for (int i = 0; i < 8; ++i) {
        int e = t + 256 * i;
        wf4[e] = ((const float4*)W)[e];
    }
    int p = t & 63, og = t >> 6;
    int g = blockIdx.x * 64 + p;
    int b = g >> 12, n = g & 4095;
    const float* xb = x + (size_t)b * NC * NPTS + n;

    float4 xr[16];
#pragma unroll
    for (int c4 = 0; c4 < 16; ++c4) {
        xr[c4].x = xb[(4 * c4 + 0) * NPTS];
        xr[c4].y = xb[(4 * c4 + 1) * NPTS];
        xr[c4].z = xb[(4 * c4 + 2) * NPTS];
        xr[c4].w = xb[(4 * c4 + 3) * NPTS];
    }
    __syncthreads();

    float out1[16], out2[16];
#pragma unroll
    for (int oi = 0; oi < 16; ++oi) {
        int o = og * 16 + oi;
        float a1 = 0.f, a2 = 0.f;
#pragma unroll
        for (int c4 = 0; c4 < 16; ++c4) {
            float4 w1 = wf4[o * 32 + c4];
            float4 w2 = wf4[o * 32 + 16 + c4];
            float4 xv = xr[c4];
            a1 += w1.x * xv.x + w1.y * xv.y + w1.z * xv.z + w1.w * xv.w;
            a2 += w2.x * xv.x + w2.y * xv.y + w2.z * xv.z + w2.w * xv.w;
        }
        out1[oi] = a1;
        out2[oi] = a2 - a1;
    }
    float4* y1p = (float4*)(y1 + (size_t)g * 64 + og * 16);
    float4* y2p = (float4*)(y2 + (size_t)g * 64 + og * 16);
#pragma unroll
    for (int q = 0; q < 4; ++q) {
        y1p[q] = make_float4(out1[4*q], out1[4*q+1], out1[4*q+2], out1[4*q+3]);
        y2p[q] = make_float4(out2[4*q], out2[4*q+1], out2[4*q+2], out2[4*q+3]);
    }
}

// ---------------------------------------------------------------------------
// Kernel C: per-channel sum/sumsq of v = y1[idx]+y2; also emits per-(g,o)
// vmax/vmin planes so the epilogue can stream.
// ---------------------------------------------------------------------------
__global__ __launch_bounds__(256, 4) void stats_kernel(
    const float* __restrict__ y1, const float* __restrict__ y2,
    const int* __restrict__ idx, float* __restrict__ part,
    float* __restrict__ mmax, float* __restrict__ mmin)
{
    int t = threadIdx.x;
    int o = t & 63, p4 = t >> 6;
    int blk = (int)blockIdx.x;
    int g0 = ((blk & 7) * 64 + (blk >> 3)) * 64;
    float s1 = 0.f, s2 = 0.f;
    for (int pi = 0; pi < 16; ++pi) {
        int g = g0 + pi * 4 + p4;
        int b = g >> 12;
        float y2v = y2[(size_t)g * 64 + o];
        const int* ip = idx + (size_t)g * KNN;
        float vmax = -FLT_MAX, vmin = FLT_MAX;
#pragma unroll
        for (int j = 0; j < KNN; ++j) {
            int id = ip[j];
            float v = y1[((size_t)(b << 12) + id) * 64 + o] + y2v;
            s1 += v; s2 += v * v;
            vmax = fmaxf(vmax, v); vmin = fminf(vmin, v);
        }
        mmax[(size_t)g * 64 + o] = vmax;
        mmin[(size_t)g * 64 + o] = vmin;
    }
    __shared__ float red[256];
    red[t] = s1; __syncthreads();
    if (t < 64) part[blockIdx.x * 128 + o] = red[o] + red[64 + o] + red[128 + o] + red[192 + o];
    __syncthreads();
    red[t] = s2; __syncthreads();
    if (t < 64) part[blockIdx.x * 128 + 64 + o] = red[o] + red[64 + o] + red[128 + o] + red[192 + o];
}

__global__ void finalize_stats_kernel(
    const float* __restrict__ part, const float* __restrict__ gamma,
    const float* __restrict__ beta, float* __restrict__ ss)
{
    int t = threadIdx.x;   // 128 threads
    float S = 0.f;
    for (int p = 0; p < 512; ++p) S += part[p * 128 + t];
    __shared__ float sm[128];
    sm[t] = S; __syncthreads();
    if (t < 64) {
        const float inv = 1.f / (float)(NB * NPTS * KNN);
        float mean = sm[t] * inv;
        float var  = sm[64 + t] * inv - mean * mean;
        float scale = gamma[t] * rsqrtf(var + 1e-5f);
        ss[t] = scale;
        ss[64 + t] = beta[t] - mean * scale;
    }
}

// ---------------------------------------------------------------------------
// Kernel E (streaming): affine+relu from minmax planes, transpose, write.
// ---------------------------------------------------------------------------
__global__ __launch_bounds__(256, 4) void epilogue_stream_kernel(
    const float* __restrict__ mmax, const float* __restrict__ mmin,
    const float* __restrict__ ss, float* __restrict__ out)
{
    __shared__ float zT[64][65];
    int t = threadIdx.x;
    int o = t & 63, p4 = t >> 6;
    float sc = ss[o], sh = ss[64 + o];
    int blk = (int)blockIdx.x;
    int g0 = ((blk & 7) * 64 + (blk >> 3)) * 64;
    int b = g0 >> 12, n0 = g0 & 4095;
    for (int pi = 0; pi < 16; ++pi) {
        int pc = pi * 4 + p4;
        int g = g0 + pc;
        float vmax = mmax[(size_t)g * 64 + o];
        float vmin = mmin[(size_t)g * 64 + o];
        float z = (sc >= 0.f) ? sc * vmax + sh : sc * vmin + sh;
        zT[o][pc] = fmaxf(z, 0.f);
    }
    __syncthreads();
    for (int i = 0; i < 16; ++i) {
        int e = t + 256 * i;
        int oo = e >> 6, nn = e & 63;
        out[((size_t)(b * 64 + oo)) * 4096 + n0 + nn] = zT[oo][nn];
    }
}

// ---------------------------------------------------------------------------
extern "C" void kernel_launch(void* const* d_in, const int* in_sizes, int n_in,
                              void* d_out, int out_size, void* d_ws, size_t ws_size,
                              hipStream_t stream)
{
    const float* x     = (const float*)d_in[0];
    const float* W     = (const float*)d_in[1];
    const float* gamma = (const float*)d_in[2];
    const float* beta  = (const float*)d_in[3];
    float* out = (float*)d_out;

    char* ws = (char*)d_ws;
    unsigned short* xs = (unsigned short*)(ws);                     // 12 MB
    unsigned long long* ptU = (unsigned long long*)(ws + 12582912); // 10.49 MB

    // tail beyond the 4-split-sized shadow (proven >= ~36.6 MB since R5)
    const size_t tail_off = 12582912ull + 20971520ull;              // 33.55 MB
    char* tail = ws + tail_off;
    int*   idx  = (int*)  (tail);
    float* xx   = (float*)(tail + 2621440);
    float* part = (float*)(tail + 2621440 + 131072);
    float* ss   = (float*)(tail + 2621440 + 131072 + 262144);
    // phase 2 overlays the dead xs+ptU region
    float* y1   = (float*)(ws);                                     // 8 MB
    float* y2   = (float*)(ws + 8388608);                           // 8 MB
    float* mmax = (float*)(ws + 16777216);                          // 8 MB
    float* mmin = (float*)(ws + 25165824);                          // 8 MB

    hipLaunchKernelGGL(split_kernel, dim3(128), dim3(256), 0, stream, x, xs, xx);
    hipLaunchKernelGGL((knn_mfma_kernel<2>), dim3(2048), dim3(128), 0, stream, xs, xx, ptU);
    hipLaunchKernelGGL((merge_kernel<2>),    dim3(128),  dim3(256), 0, stream, ptU, idx);
    hipLaunchKernelGGL(precompute_kernel, dim3(512), dim3(256), 0, stream, x, W, y1, y2);
    hipLaunchKernelGGL(stats_kernel,          dim3(512), dim3(256), 0, stream, y1, y2, idx, part, mmax, mmin);
    hipLaunchKernelGGL(finalize_stats_kernel, dim3(1),   dim3(128), 0, stream, part, gamma, beta, ss);
    hipLaunchKernelGGL(epilogue_stream_kernel, dim3(512), dim3(256), 0, stream, mmax, mmin, ss, out);
}